// Round 16
// baseline (1383.893 us; speedup 1.0000x reference)
//
#include <hip/hip_runtime.h>
#include <hip/hip_bf16.h>
#include <cstdint>
#include <cstddef>

// ---------------------------------------------------------------------------
// QuantizedAttention (MX int8 block quant, exponent-sign top-k mask)
// B=4 N=1024 C=768 H=12 Dh=64 TOPK=20 BLOCK=32
// r16 key semantic: exponent_sign uses the JAX-FAITHFUL log2:
//   jnp.log2(x) == lax.log(x) / lax.log(2)   (f32 division!)
// emulated as f32(log(f64 x)) / 0.69314718246459961f. Its floor flips in a
// band DISJOINT from exact/CR/musl log2 (all tested, all bit-identical) —
// including at exact powers of two. esig applied to SCALED q (0.125f*v;
// division-log2 does not commute with pow2 scaling) and raw k.
// Everything else = r12 (best config): RNE bf16, asc ties, k-seq BLAS sums,
// np-pairwise denominator, CR exp.
// ---------------------------------------------------------------------------

typedef __attribute__((ext_vector_type(8))) short short8;
typedef __attribute__((ext_vector_type(4))) float f32x4;
typedef unsigned short ushort_t;

#define DEV static __device__ __forceinline__

constexpr int BATCH = 4, SEQ = 1024, CDIM = 768, HEADS = 12, DH = 64;
constexpr int ROWS = BATCH * SEQ;          // 4096
constexpr int BHT = BATCH * HEADS;         // 48
constexpr int TOPK = 20;

DEV float bf16rne(float x) {
  unsigned u = __float_as_uint(x);
  u += 0x7fffu + ((u >> 16) & 1u);
  return __uint_as_float(u & 0xffff0000u);
}
DEV ushort_t f2bf(float x) {
  unsigned u = __float_as_uint(x);
  u += 0x7fffu + ((u >> 16) & 1u);
  return (ushort_t)(u >> 16);
}
DEV float bf2f(ushort_t b) { return __uint_as_float(((unsigned)b) << 16); }
// exact floor(log2) — used for MX shared_exp (bf16-valued amax, robust)
DEV int flog2(float ax) { int e; (void)frexpf(ax, &e); return e - 1; }
DEV float mxq(float xb, float scale) {
  float q = rintf(xb / scale);              // round half to even; /pow2 exact
  q = fminf(fmaxf(q, -127.f), 127.f);
  return q * scale;
}
DEV unsigned ordf(float p) {
  if (p == 0.f) return 0x80000000u;
  unsigned u = __float_as_uint(p);
  return (u & 0x80000000u) ? ~u : (u | 0x80000000u);
}

// jax-faithful log2: f32 CR log divided by f32 log(2) constant
DEV float esig_jax(float v) {
  float ax = fabsf(v);
  if (!(ax > 0.f)) return 0.f;
  float lg = (float)log((double)ax);                 // ~CR f32 log
  float l2 = lg / 0.69314718246459960938f;           // f32 division by fl(ln2)
  float fl = floorf(l2);
  return copysignf(exp2f(fl), v);                    // exp2 of integer: exact
}

// ---------------------------------------------------------------------------
// mx_quant(bf16_quant(x), axis=-1) for row-major [R, C], C % 32 == 0.
// ---------------------------------------------------------------------------
__global__ __launch_bounds__(256) void quant_rows(const float* __restrict__ in,
                                                  ushort_t* __restrict__ out) {
  int gid = blockIdx.x * 256 + threadIdx.x;
  float xb = bf16rne(in[gid]);
  float a = fabsf(xb);
#pragma unroll
  for (int off = 16; off; off >>= 1) a = fmaxf(a, __shfl_xor(a, off, 32));
  int e = flog2(a > 0.f ? a : 1.f);
  float scale = ldexpf(1.f, e - 6);
  out[gid] = f2bf(mxq(xb, scale));
}

// ---------------------------------------------------------------------------
// k-sequential f32 GEMM (BLAS model): C = f32seq(A[M,K]*B[N,K]^T) + bias
// ---------------------------------------------------------------------------
__global__ __launch_bounds__(256) void gemm_f32_bt(const ushort_t* __restrict__ A,
                                                   const ushort_t* __restrict__ Bm,
                                                   const float* __restrict__ bias,
                                                   float* __restrict__ C,
                                                   int M, int N, int K) {
  constexpr int KS = 36;
  __shared__ ushort_t As[64][KS];
  __shared__ ushort_t Bs[64][KS];
  const int tid = threadIdx.x;
  const int ty = tid >> 4, tx = tid & 15;
  const int m0 = blockIdx.y * 64, n0 = blockIdx.x * 64;
  float acc[4][4] = {};
  const int sr = tid >> 2, sc = (tid & 3) * 8;

  for (int k0 = 0; k0 < K; k0 += 32) {
    const ushort_t* ag = A + (size_t)(m0 + sr) * K + k0 + sc;
    const ushort_t* bg = Bm + (size_t)(n0 + sr) * K + k0 + sc;
    *reinterpret_cast<uint2*>(&As[sr][sc])     = *reinterpret_cast<const uint2*>(ag);
    *reinterpret_cast<uint2*>(&As[sr][sc + 4]) = *reinterpret_cast<const uint2*>(ag + 4);
    *reinterpret_cast<uint2*>(&Bs[sr][sc])     = *reinterpret_cast<const uint2*>(bg);
    *reinterpret_cast<uint2*>(&Bs[sr][sc + 4]) = *reinterpret_cast<const uint2*>(bg + 4);
    __syncthreads();
#pragma unroll
    for (int kk = 0; kk < 32; kk += 4) {
      float a4[4][4], b4[4][4];
#pragma unroll
      for (int i = 0; i < 4; ++i) {
        ushort4 av = *reinterpret_cast<const ushort4*>(&As[ty * 4 + i][kk]);
        a4[i][0] = bf2f(av.x); a4[i][1] = bf2f(av.y);
        a4[i][2] = bf2f(av.z); a4[i][3] = bf2f(av.w);
        ushort4 bv = *reinterpret_cast<const ushort4*>(&Bs[i * 16 + tx][kk]);
        b4[i][0] = bf2f(bv.x); b4[i][1] = bf2f(bv.y);
        b4[i][2] = bf2f(bv.z); b4[i][3] = bf2f(bv.w);
      }
#pragma unroll
      for (int i = 0; i < 4; ++i)
#pragma unroll
        for (int j = 0; j < 4; ++j) {
#pragma unroll
          for (int l = 0; l < 4; ++l)
            acc[i][j] = fmaf(a4[i][l], b4[j][l], acc[i][j]);   // k-ascending
        }
    }
    __syncthreads();
  }
#pragma unroll
  for (int i = 0; i < 4; ++i)
#pragma unroll
    for (int j = 0; j < 4; ++j) {
      int row = m0 + ty * 4 + i, col = n0 + j * 16 + tx;
      C[(size_t)row * N + col] = acc[i][j] + bias[col];
    }
}

// ---------------------------------------------------------------------------
// bf16 MFMA GEMM (f32 accumulate) — final projection only.
// ---------------------------------------------------------------------------
__global__ __launch_bounds__(256) void gemm_bt(const ushort_t* __restrict__ A,
                                               const ushort_t* __restrict__ Bm,
                                               const float* __restrict__ bias,
                                               float* __restrict__ C,
                                               int M, int N, int K) {
  constexpr int KS = 40;
  __shared__ ushort_t As[64][KS];
  __shared__ ushort_t Bs[64][KS];
  const int tid = threadIdx.x;
  const int w = tid >> 6, lane = tid & 63;
  const int wm = w >> 1, wn = w & 1;
  const int m0 = blockIdx.y * 64, n0 = blockIdx.x * 64;

  f32x4 acc[2][2];
#pragma unroll
  for (int i = 0; i < 2; ++i)
#pragma unroll
    for (int j = 0; j < 2; ++j) acc[i][j] = (f32x4){0.f, 0.f, 0.f, 0.f};

  const int sr = tid >> 2, sc = (tid & 3) * 8;
  for (int k0 = 0; k0 < K; k0 += 32) {
    *reinterpret_cast<uint4*>(&As[sr][sc]) =
        *reinterpret_cast<const uint4*>(A + (size_t)(m0 + sr) * K + k0 + sc);
    *reinterpret_cast<uint4*>(&Bs[sr][sc]) =
        *reinterpret_cast<const uint4*>(Bm + (size_t)(n0 + sr) * K + k0 + sc);
    __syncthreads();
    const int fr = lane & 15, koff = (lane >> 4) * 8;
    short8 av[2], bv[2];
#pragma unroll
    for (int f = 0; f < 2; ++f) {
      av[f] = *reinterpret_cast<const short8*>(&As[wm * 32 + f * 16 + fr][koff]);
      bv[f] = *reinterpret_cast<const short8*>(&Bs[wn * 32 + f * 16 + fr][koff]);
    }
#pragma unroll
    for (int fm = 0; fm < 2; ++fm)
#pragma unroll
      for (int fn = 0; fn < 2; ++fn)
        acc[fm][fn] = __builtin_amdgcn_mfma_f32_16x16x32_bf16(av[fm], bv[fn], acc[fm][fn], 0, 0, 0);
    __syncthreads();
  }
  const int cl = lane & 15, rq = (lane >> 4) * 4;
#pragma unroll
  for (int fm = 0; fm < 2; ++fm)
#pragma unroll
    for (int fn = 0; fn < 2; ++fn) {
      int col = n0 + wn * 32 + fn * 16 + cl;
      float bb = bias[col];
#pragma unroll
      for (int j = 0; j < 4; ++j) {
        int row = m0 + wm * 32 + fm * 16 + rq + j;
        C[(size_t)row * N + col] = acc[fm][fn][j] + bb;
      }
    }
}

// ---------------------------------------------------------------------------
// build q/k per-head quantized bf16 + exponent-sign arrays from f32 qkv.
// eq = esig_jax(0.125f * q); ek = esig_jax(k).
// ---------------------------------------------------------------------------
__global__ __launch_bounds__(256) void build_qke(const float* __restrict__ qkv,
                                                 ushort_t* __restrict__ qq,
                                                 ushort_t* __restrict__ qk,
                                                 float* __restrict__ eqr,
                                                 float* __restrict__ ekr) {
  const int HALF = ROWS * CDIM;
  int gid = blockIdx.x * 256 + threadIdx.x;
  int s = (gid >= HALF) ? 1 : 0;
  int rem = gid - s * HALF;
  int row = rem / CDIM, c = rem % CDIM;
  float v = qkv[(size_t)row * 2304 + s * CDIM + c];

  float es = esig_jax(s == 0 ? 0.125f * v : v);
  float xb = bf16rne(v);
  float a = fabsf(xb);
#pragma unroll
  for (int off = 16; off; off >>= 1) a = fmaxf(a, __shfl_xor(a, off, 32));
  int e = flog2(a > 0.f ? a : 1.f);
  float scale = ldexpf(1.f, e - 6);
  ushort_t qb = f2bf(mxq(xb, scale));

  int h = c >> 6, d = c & 63, b = row >> 10, n = row & 1023;
  size_t dst = ((size_t)((b * HEADS + h) << 10) + n) * 64 + d;
  if (s == 0) { qq[dst] = qb; eqr[dst] = es; }
  else        { qk[dst] = qb; ekr[dst] = es; }
}

// ---------------------------------------------------------------------------
// v quantized along N (axis=-2): per (bh, d) column, 32-row blocks.
// ---------------------------------------------------------------------------
__global__ __launch_bounds__(64) void build_qv(const float* __restrict__ qkv,
                                               ushort_t* __restrict__ qv) {
  int bh = blockIdx.x >> 5, nb = blockIdx.x & 31;
  int b = bh / HEADS, h = bh - b * HEADS;
  int d = threadIdx.x;
  float xs[32];
  float am = 0.f;
#pragma unroll
  for (int i = 0; i < 32; ++i) {
    int n = nb * 32 + i;
    float xb = bf16rne(qkv[(size_t)((b << 10) + n) * 2304 + 1536 + h * 64 + d]);
    xs[i] = xb;
    am = fmaxf(am, fabsf(xb));
  }
  int e = flog2(am > 0.f ? am : 1.f);
  float scale = ldexpf(1.f, e - 6);
#pragma unroll
  for (int i = 0; i < 32; ++i)
    qv[((size_t)(bh << 10) + nb * 32 + i) * 64 + d] = f2bf(mxq(xs[i], scale));
}

// ---------------------------------------------------------------------------
// pred[bhc, r, j] = f32 k-seq( eq[r,:] * ek[j,:] )
// (eq now carries the global 0.125 scale — ranking unchanged, values faithful)
// ---------------------------------------------------------------------------
__global__ __launch_bounds__(256) void pred_kernel(const float* __restrict__ eqr,
                                                   const float* __restrict__ ekr,
                                                   float* __restrict__ pred,
                                                   int bh0) {
  constexpr int LS = 66;
  __shared__ float eqs[64][LS];
  __shared__ float eks[64][LS];
  int bhc = blockIdx.z, bh = bh0 + bhc;
  int rt = blockIdx.y, kt = blockIdx.x;
  int tid = threadIdx.x;

  const float* eqg = eqr + ((size_t)bh << 16) + (size_t)rt * 64 * 64;
  const float* ekg = ekr + ((size_t)bh << 16) + (size_t)kt * 64 * 64;
#pragma unroll
  for (int it = 0; it < 16; ++it) {
    int flat = it * 256 + tid;
    int r = flat >> 6, d = flat & 63;
    eqs[r][d] = eqg[flat];
    eks[r][d] = ekg[flat];
  }
  __syncthreads();

  int ty = tid >> 4, tx = tid & 15;
  float acc[4][4] = {};
  for (int d = 0; d < 64; d += 2) {
    float da[4][2], db[4][2];
#pragma unroll
    for (int i = 0; i < 4; ++i) {
      float2 t = *reinterpret_cast<const float2*>(&eqs[ty * 4 + i][d]);
      da[i][0] = t.x; da[i][1] = t.y;
      float2 u = *reinterpret_cast<const float2*>(&eks[tx * 4 + i][d]);
      db[i][0] = u.x; db[i][1] = u.y;
    }
#pragma unroll
    for (int i = 0; i < 4; ++i)
#pragma unroll
      for (int j = 0; j < 4; ++j) {
        acc[i][j] = fmaf(da[i][0], db[j][0], acc[i][j]);   // d-ascending
        acc[i][j] = fmaf(da[i][1], db[j][1], acc[i][j]);
      }
  }

  float* po = pred + ((size_t)((bhc << 10) + rt * 64)) * 1024 + kt * 64;
#pragma unroll
  for (int i = 0; i < 4; ++i) {
    float4 o;
    o.x = acc[i][0]; o.y = acc[i][1]; o.z = acc[i][2]; o.w = acc[i][3];
    *reinterpret_cast<float4*>(&po[(size_t)(ty * 4 + i) * 1024 + tx * 4]) = o;
  }
}

// ---------------------------------------------------------------------------
// per row (1 wave): top-20 (value desc, index asc) -> sort asc ->
//   logits: strict k-seq f32 fold; denom: np-pairwise buckets; P.V: k-seq
// -> probs bf16 + MX quant -> fused output MX quant -> qout (bf16).
// ---------------------------------------------------------------------------
__global__ __launch_bounds__(256) void topk_attn(const float* __restrict__ pred,
                                                 const ushort_t* __restrict__ qq,
                                                 const ushort_t* __restrict__ qk,
                                                 const ushort_t* __restrict__ qv,
                                                 ushort_t* __restrict__ qout,
                                                 int bh0) {
  __shared__ unsigned sidx[4][TOPK];
  __shared__ unsigned sj[4][TOPK];

  const int w = threadIdx.x >> 6, lane = threadIdx.x & 63;
  const int rl = blockIdx.x * 4 + w;
  const int bhc = rl >> 10, n = rl & 1023;
  const int bh = bh0 + bhc;
  const int b = bh / HEADS, h = bh - b * HEADS;

  const float* prow = pred + (size_t)rl * 1024;
  unsigned long long key[16];
#pragma unroll
  for (int t = 0; t < 16; ++t) {
    float v = prow[t * 64 + lane];
    key[t] = (((unsigned long long)ordf(v)) << 32) | (unsigned)(1023 - (t * 64 + lane));
  }

  for (int it = 0; it < TOPK; ++it) {
    unsigned long long m = key[0];
#pragma unroll
    for (int t = 1; t < 16; ++t) m = (key[t] > m) ? key[t] : m;
#pragma unroll
    for (int off = 32; off; off >>= 1) {
      unsigned long long o = __shfl_xor(m, off);
      m = (o > m) ? o : m;
    }
    if (lane == 0) sidx[w][it] = 1023u - (unsigned)(m & 0xffffffffu);
#pragma unroll
    for (int t = 0; t < 16; ++t) key[t] = (key[t] == m) ? 0ull : key[t];
  }

  // sort selected indices ascending (indices distinct)
  if (lane < TOPK) {
    unsigned myj0 = sidx[w][lane];
    int rank = 0;
    for (int k2 = 0; k2 < TOPK; ++k2) rank += (sidx[w][k2] < myj0) ? 1 : 0;
    sj[w][rank] = myj0;
  }

  // attn logits: strict k-sequential f32 fold (k = lane index 0..63)
  float qqv = bf2f(qq[((size_t)(bh << 10) + n) * 64 + lane]);
  float attv = -__builtin_inff();
  for (int i = 0; i < TOPK; ++i) {
    unsigned j = sj[w][i];
    float p = qqv * bf2f(qk[((size_t)(bh << 10) + j) * 64 + lane]);  // exact
    float s = 0.f;
#pragma unroll
    for (int k2 = 0; k2 < 64; ++k2) s += __shfl(p, k2);   // k-ascending serial
    if (lane == i) attv = s * 0.125f;   // exact pow2 scale (commutes)
  }

  // softmax max (exact)
  float mx = attv;
#pragma unroll
  for (int off = 32; off; off >>= 1) mx = fmaxf(mx, __shfl_xor(mx, off));
  float ev = (lane < TOPK) ? (float)exp((double)(attv - mx)) : 0.f;

  // np pairwise denominator over the virtual 1024-row: bucket (j>>7, j&7)
  float r = 0.f;
  {
    int Bk = lane >> 3, a = lane & 7;
    for (int i = 0; i < TOPK; ++i) {
      unsigned jj = sj[w][i];
      float evi = __shfl(ev, i);
      if ((int)(jj >> 7) == Bk && (int)(jj & 7) == a) r += evi;
    }
  }
#pragma unroll
  for (int off = 1; off < 64; off <<= 1) r += __shfl_xor(r, off);
  float denom = r;

  float pf = (lane < TOPK) ? (ev / denom) : 0.f;

  // bf16(probs) then MX quant along key axis (j>>5 blocks)
  float pb = bf16rne(pf);
  unsigned myj = (lane < TOPK) ? sj[w][lane] : 0xffffffffu;
  unsigned g = myj >> 5;
  float am = 0.f;
  for (int k2 = 0; k2 < TOPK; ++k2) {
    unsigned oj = __shfl(myj, k2);
    float ov = __shfl(pb, k2);
    if ((oj >> 5) == g) am = fmaxf(am, fabsf(ov));
  }
  int e = flog2(am > 0.f ? am : 1.f);
  float scale = ldexpf(1.f, e - 6);
  float qp = mxq(pb, scale);

  // P.V: k-seq ascending-index fold (lane = d; products exact)
  float o = 0.f;
  for (int i = 0; i < TOPK; ++i) {
    float wq = __shfl(qp, i);
    unsigned j = sj[w][i];
    o = fmaf(wq, bf2f(qv[((size_t)(bh << 10) + j) * 64 + lane]), o);
  }
  float xb2 = bf16rne(o);
  float am2 = fabsf(xb2);
#pragma unroll
  for (int off = 16; off; off >>= 1) am2 = fmaxf(am2, __shfl_xor(am2, off, 32));
  int e2 = flog2(am2 > 0.f ? am2 : 1.f);
  float sc2 = ldexpf(1.f, e2 - 6);
  qout[((size_t)((b << 10) + n)) * CDIM + h * 64 + lane] = f2bf(mxq(xb2, sc2));
}

// ---------------------------------------------------------------------------
// Host launcher
// ---------------------------------------------------------------------------
extern "C" void kernel_launch(void* const* d_in, const int* in_sizes, int n_in,
                              void* d_out, int out_size, void* d_ws, size_t ws_size,
                              hipStream_t stream) {
  (void)in_sizes; (void)n_in; (void)out_size;
  const float* x      = (const float*)d_in[0];
  const float* qkv_w  = (const float*)d_in[1];
  const float* qkv_b  = (const float*)d_in[2];
  const float* proj_w = (const float*)d_in[3];
  const float* proj_b = (const float*)d_in[4];
  float* out = (float*)d_out;

  size_t off = 0;
  auto alloc = [&](size_t bytes) -> void* {
    void* p = (char*)d_ws + off;
    off = (off + bytes + 255) & ~(size_t)255;
    return p;
  };
  ushort_t* qx   = (ushort_t*)alloc((size_t)ROWS * CDIM * 2);
  ushort_t* qw   = (ushort_t*)alloc((size_t)2304 * CDIM * 2);
  ushort_t* qq   = (ushort_t*)alloc((size_t)BHT * SEQ * DH * 2);
  ushort_t* qk   = (ushort_t*)alloc((size_t)BHT * SEQ * DH * 2);
  float*    eqr  = (float*)alloc((size_t)BHT * SEQ * DH * 4);
  float*    ekr  = (float*)alloc((size_t)BHT * SEQ * DH * 4);
  ushort_t* qv   = (ushort_t*)alloc((size_t)BHT * SEQ * DH * 2);
  ushort_t* qout = (ushort_t*)alloc((size_t)ROWS * CDIM * 2);
  ushort_t* qpw  = (ushort_t*)alloc((size_t)CDIM * CDIM * 2);
  float*    qkv  = (float*)alloc((size_t)ROWS * 2304 * 4);

  const size_t per_bh = (size_t)SEQ * SEQ * 4;
  static const int divs[] = {48, 24, 16, 12, 8, 6, 4, 3, 2, 1};
  int CB = 1;
  for (int i = 0; i < 10; ++i)
    if (off + (size_t)divs[i] * per_bh + 256 <= ws_size) { CB = divs[i]; break; }
  float* pred = (float*)alloc((size_t)CB * per_bh);

  // 1) MX quantize inputs
  quant_rows<<<(ROWS * CDIM) / 256, 256, 0, stream>>>(x, qx);
  quant_rows<<<(2304 * CDIM) / 256, 256, 0, stream>>>(qkv_w, qw);
  quant_rows<<<(CDIM * CDIM) / 256, 256, 0, stream>>>(proj_w, qpw);

  // 2) qkv = f32 k-seq(qx @ qw^T) + bias, then per-head builds
  gemm_f32_bt<<<dim3(2304 / 64, ROWS / 64), 256, 0, stream>>>(
      qx, qw, qkv_b, qkv, ROWS, 2304, CDIM);
  build_qke<<<(2 * ROWS * CDIM) / 256, 256, 0, stream>>>(qkv, qq, qk, eqr, ekr);
  build_qv<<<BHT * 32, 64, 0, stream>>>(qkv, qv);

  // 3) chunked: pred + fused topk/attn/softmax/PV/out-quant
  for (int bh0 = 0; bh0 < BHT; bh0 += CB) {
    pred_kernel<<<dim3(16, 16, CB), 256, 0, stream>>>(eqr, ekr, pred, bh0);
    topk_attn<<<CB * (SEQ / 4), 256, 0, stream>>>(pred, qq, qk, qv, qout, bh0);
  }

  // 4) final projection (f32 MFMA — no discrete decisions downstream)
  gemm_bt<<<dim3(CDIM / 64, ROWS / 64), 256, 0, stream>>>(qout, qpw, proj_b, out,
                                                          ROWS, CDIM, CDIM);
}

// Round 17
// 911.118 us; speedup vs baseline: 1.5189x; 1.5189x over previous
//
#include <hip/hip_runtime.h>
#include <hip/hip_bf16.h>
#include <cstdint>
#include <cstddef>

// ---------------------------------------------------------------------------
// QuantizedAttention (MX int8 block quant, exponent-sign top-k mask)
// B=4 N=1024 C=768 H=12 Dh=64 TOPK=20 BLOCK=32
// PASSING semantics (r16), all decision-path numerics preserved BIT-EXACTLY:
//   - exponent_sign = jax-faithful log2: f32(log(f64 x)) / fl32(ln2), floor.
//     eq from 0.125f*q (division-log2 does not commute with pow2), ek raw.
//   - bf16 = RNE; top-k (value desc, index asc); k-seq BLAS sums;
//     np-pairwise softmax denominator; CR exp (f64->f32).
// r17 = performance only:
//   - topk_attn: logits products staged to LDS, per-lane ordered fold
//     (same add order; mul/add split by LDS -> no contraction);
//     selection with cached per-lane max (same argmax sequence).
//   - gemm_f32_bt: 64x128 tile, 4x8 per thread (thread remap only).
// ---------------------------------------------------------------------------

typedef __attribute__((ext_vector_type(8))) short short8;
typedef __attribute__((ext_vector_type(4))) float f32x4;
typedef unsigned short ushort_t;

#define DEV static __device__ __forceinline__

constexpr int BATCH = 4, SEQ = 1024, CDIM = 768, HEADS = 12, DH = 64;
constexpr int ROWS = BATCH * SEQ;          // 4096
constexpr int BHT = BATCH * HEADS;         // 48
constexpr int TOPK = 20;

DEV float bf16rne(float x) {
  unsigned u = __float_as_uint(x);
  u += 0x7fffu + ((u >> 16) & 1u);
  return __uint_as_float(u & 0xffff0000u);
}
DEV ushort_t f2bf(float x) {
  unsigned u = __float_as_uint(x);
  u += 0x7fffu + ((u >> 16) & 1u);
  return (ushort_t)(u >> 16);
}
DEV float bf2f(ushort_t b) { return __uint_as_float(((unsigned)b) << 16); }
// exact floor(log2) — used for MX shared_exp (bf16-valued amax, robust)
DEV int flog2(float ax) { int e; (void)frexpf(ax, &e); return e - 1; }
DEV float mxq(float xb, float scale) {
  float q = rintf(xb / scale);              // round half to even; /pow2 exact
  q = fminf(fmaxf(q, -127.f), 127.f);
  return q * scale;
}
DEV unsigned ordf(float p) {
  if (p == 0.f) return 0x80000000u;
  unsigned u = __float_as_uint(p);
  return (u & 0x80000000u) ? ~u : (u | 0x80000000u);
}

// jax-faithful log2: f32 CR log divided by f32 log(2) constant
DEV float esig_jax(float v) {
  float ax = fabsf(v);
  if (!(ax > 0.f)) return 0.f;
  float lg = (float)log((double)ax);                 // ~CR f32 log
  float l2 = lg / 0.69314718246459960938f;           // f32 division by fl(ln2)
  float fl = floorf(l2);
  return copysignf(exp2f(fl), v);                    // exp2 of integer: exact
}

// ---------------------------------------------------------------------------
// mx_quant(bf16_quant(x), axis=-1) for row-major [R, C], C % 32 == 0.
// ---------------------------------------------------------------------------
__global__ __launch_bounds__(256) void quant_rows(const float* __restrict__ in,
                                                  ushort_t* __restrict__ out) {
  int gid = blockIdx.x * 256 + threadIdx.x;
  float xb = bf16rne(in[gid]);
  float a = fabsf(xb);
#pragma unroll
  for (int off = 16; off; off >>= 1) a = fmaxf(a, __shfl_xor(a, off, 32));
  int e = flog2(a > 0.f ? a : 1.f);
  float scale = ldexpf(1.f, e - 6);
  out[gid] = f2bf(mxq(xb, scale));
}

// ---------------------------------------------------------------------------
// k-sequential f32 GEMM (BLAS model): C = f32seq(A[M,K]*B[N,K]^T) + bias
// 64x128 tile, 256 threads, 4x8 outputs/thread. Per-output math identical
// to r16 (single f32 accumulator, strict k-ascending fmaf).
// Requires N % 128 == 0.
// ---------------------------------------------------------------------------
__global__ __launch_bounds__(256) void gemm_f32_bt(const ushort_t* __restrict__ A,
                                                   const ushort_t* __restrict__ Bm,
                                                   const float* __restrict__ bias,
                                                   float* __restrict__ C,
                                                   int M, int N, int K) {
  constexpr int KS = 36;
  __shared__ ushort_t As[64][KS];
  __shared__ ushort_t Bs[128][KS];
  const int tid = threadIdx.x;
  const int ty = tid >> 4, tx = tid & 15;      // ty 0..15 (4 rows each)
  const int m0 = blockIdx.y * 64, n0 = blockIdx.x * 128;
  float acc[4][8] = {};
  const int sr = tid >> 2, sc = (tid & 3) * 8;   // A staging: 64x32
  const int br = tid >> 1, bc = (tid & 1) * 16;  // B staging: 128x32

  for (int k0 = 0; k0 < K; k0 += 32) {
    const ushort_t* ag = A + (size_t)(m0 + sr) * K + k0 + sc;
    *reinterpret_cast<uint2*>(&As[sr][sc])     = *reinterpret_cast<const uint2*>(ag);
    *reinterpret_cast<uint2*>(&As[sr][sc + 4]) = *reinterpret_cast<const uint2*>(ag + 4);
    const ushort_t* bg = Bm + (size_t)(n0 + br) * K + k0 + bc;
    *reinterpret_cast<uint2*>(&Bs[br][bc])      = *reinterpret_cast<const uint2*>(bg);
    *reinterpret_cast<uint2*>(&Bs[br][bc + 4])  = *reinterpret_cast<const uint2*>(bg + 4);
    *reinterpret_cast<uint2*>(&Bs[br][bc + 8])  = *reinterpret_cast<const uint2*>(bg + 8);
    *reinterpret_cast<uint2*>(&Bs[br][bc + 12]) = *reinterpret_cast<const uint2*>(bg + 12);
    __syncthreads();
#pragma unroll
    for (int kk = 0; kk < 32; kk += 4) {
      float a4[4][4], b4[8][4];
#pragma unroll
      for (int i = 0; i < 4; ++i) {
        ushort4 av = *reinterpret_cast<const ushort4*>(&As[ty * 4 + i][kk]);
        a4[i][0] = bf2f(av.x); a4[i][1] = bf2f(av.y);
        a4[i][2] = bf2f(av.z); a4[i][3] = bf2f(av.w);
      }
#pragma unroll
      for (int j = 0; j < 8; ++j) {
        ushort4 bv = *reinterpret_cast<const ushort4*>(&Bs[j * 16 + tx][kk]);
        b4[j][0] = bf2f(bv.x); b4[j][1] = bf2f(bv.y);
        b4[j][2] = bf2f(bv.z); b4[j][3] = bf2f(bv.w);
      }
#pragma unroll
      for (int i = 0; i < 4; ++i)
#pragma unroll
        for (int j = 0; j < 8; ++j) {
#pragma unroll
          for (int l = 0; l < 4; ++l)
            acc[i][j] = fmaf(a4[i][l], b4[j][l], acc[i][j]);   // k-ascending
        }
    }
    __syncthreads();
  }
#pragma unroll
  for (int i = 0; i < 4; ++i)
#pragma unroll
    for (int j = 0; j < 8; ++j) {
      int row = m0 + ty * 4 + i, col = n0 + j * 16 + tx;
      C[(size_t)row * N + col] = acc[i][j] + bias[col];
    }
}

// ---------------------------------------------------------------------------
// bf16 MFMA GEMM (f32 accumulate) — final projection only.
// ---------------------------------------------------------------------------
__global__ __launch_bounds__(256) void gemm_bt(const ushort_t* __restrict__ A,
                                               const ushort_t* __restrict__ Bm,
                                               const float* __restrict__ bias,
                                               float* __restrict__ C,
                                               int M, int N, int K) {
  constexpr int KS = 40;
  __shared__ ushort_t As[64][KS];
  __shared__ ushort_t Bs[64][KS];
  const int tid = threadIdx.x;
  const int w = tid >> 6, lane = tid & 63;
  const int wm = w >> 1, wn = w & 1;
  const int m0 = blockIdx.y * 64, n0 = blockIdx.x * 64;

  f32x4 acc[2][2];
#pragma unroll
  for (int i = 0; i < 2; ++i)
#pragma unroll
    for (int j = 0; j < 2; ++j) acc[i][j] = (f32x4){0.f, 0.f, 0.f, 0.f};

  const int sr = tid >> 2, sc = (tid & 3) * 8;
  for (int k0 = 0; k0 < K; k0 += 32) {
    *reinterpret_cast<uint4*>(&As[sr][sc]) =
        *reinterpret_cast<const uint4*>(A + (size_t)(m0 + sr) * K + k0 + sc);
    *reinterpret_cast<uint4*>(&Bs[sr][sc]) =
        *reinterpret_cast<const uint4*>(Bm + (size_t)(n0 + sr) * K + k0 + sc);
    __syncthreads();
    const int fr = lane & 15, koff = (lane >> 4) * 8;
    short8 av[2], bv[2];
#pragma unroll
    for (int f = 0; f < 2; ++f) {
      av[f] = *reinterpret_cast<const short8*>(&As[wm * 32 + f * 16 + fr][koff]);
      bv[f] = *reinterpret_cast<const short8*>(&Bs[wn * 32 + f * 16 + fr][koff]);
    }
#pragma unroll
    for (int fm = 0; fm < 2; ++fm)
#pragma unroll
      for (int fn = 0; fn < 2; ++fn)
        acc[fm][fn] = __builtin_amdgcn_mfma_f32_16x16x32_bf16(av[fm], bv[fn], acc[fm][fn], 0, 0, 0);
    __syncthreads();
  }
  const int cl = lane & 15, rq = (lane >> 4) * 4;
#pragma unroll
  for (int fm = 0; fm < 2; ++fm)
#pragma unroll
    for (int fn = 0; fn < 2; ++fn) {
      int col = n0 + wn * 32 + fn * 16 + cl;
      float bb = bias[col];
#pragma unroll
      for (int j = 0; j < 4; ++j) {
        int row = m0 + wm * 32 + fm * 16 + rq + j;
        C[(size_t)row * N + col] = acc[fm][fn][j] + bb;
      }
    }
}

// ---------------------------------------------------------------------------
// build q/k per-head quantized bf16 + exponent-sign arrays from f32 qkv.
// eq = esig_jax(0.125f * q); ek = esig_jax(k).
// ---------------------------------------------------------------------------
__global__ __launch_bounds__(256) void build_qke(const float* __restrict__ qkv,
                                                 ushort_t* __restrict__ qq,
                                                 ushort_t* __restrict__ qk,
                                                 float* __restrict__ eqr,
                                                 float* __restrict__ ekr) {
  const int HALF = ROWS * CDIM;
  int gid = blockIdx.x * 256 + threadIdx.x;
  int s = (gid >= HALF) ? 1 : 0;
  int rem = gid - s * HALF;
  int row = rem / CDIM, c = rem % CDIM;
  float v = qkv[(size_t)row * 2304 + s * CDIM + c];

  float es = esig_jax(s == 0 ? 0.125f * v : v);
  float xb = bf16rne(v);
  float a = fabsf(xb);
#pragma unroll
  for (int off = 16; off; off >>= 1) a = fmaxf(a, __shfl_xor(a, off, 32));
  int e = flog2(a > 0.f ? a : 1.f);
  float scale = ldexpf(1.f, e - 6);
  ushort_t qb = f2bf(mxq(xb, scale));

  int h = c >> 6, d = c & 63, b = row >> 10, n = row & 1023;
  size_t dst = ((size_t)((b * HEADS + h) << 10) + n) * 64 + d;
  if (s == 0) { qq[dst] = qb; eqr[dst] = es; }
  else        { qk[dst] = qb; ekr[dst] = es; }
}

// ---------------------------------------------------------------------------
// v quantized along N (axis=-2): per (bh, d) column, 32-row blocks.
// ---------------------------------------------------------------------------
__global__ __launch_bounds__(64) void build_qv(const float* __restrict__ qkv,
                                               ushort_t* __restrict__ qv) {
  int bh = blockIdx.x >> 5, nb = blockIdx.x & 31;
  int b = bh / HEADS, h = bh - b * HEADS;
  int d = threadIdx.x;
  float xs[32];
  float am = 0.f;
#pragma unroll
  for (int i = 0; i < 32; ++i) {
    int n = nb * 32 + i;
    float xb = bf16rne(qkv[(size_t)((b << 10) + n) * 2304 + 1536 + h * 64 + d]);
    xs[i] = xb;
    am = fmaxf(am, fabsf(xb));
  }
  int e = flog2(am > 0.f ? am : 1.f);
  float scale = ldexpf(1.f, e - 6);
#pragma unroll
  for (int i = 0; i < 32; ++i)
    qv[((size_t)(bh << 10) + nb * 32 + i) * 64 + d] = f2bf(mxq(xs[i], scale));
}

// ---------------------------------------------------------------------------
// pred[bhc, r, j] = f32 k-seq( eq[r,:] * ek[j,:] )
// ---------------------------------------------------------------------------
__global__ __launch_bounds__(256) void pred_kernel(const float* __restrict__ eqr,
                                                   const float* __restrict__ ekr,
                                                   float* __restrict__ pred,
                                                   int bh0) {
  constexpr int LS = 66;
  __shared__ float eqs[64][LS];
  __shared__ float eks[64][LS];
  int bhc = blockIdx.z, bh = bh0 + bhc;
  int rt = blockIdx.y, kt = blockIdx.x;
  int tid = threadIdx.x;

  const float* eqg = eqr + ((size_t)bh << 16) + (size_t)rt * 64 * 64;
  const float* ekg = ekr + ((size_t)bh << 16) + (size_t)kt * 64 * 64;
#pragma unroll
  for (int it = 0; it < 16; ++it) {
    int flat = it * 256 + tid;
    int r = flat >> 6, d = flat & 63;
    eqs[r][d] = eqg[flat];
    eks[r][d] = ekg[flat];
  }
  __syncthreads();

  int ty = tid >> 4, tx = tid & 15;
  float acc[4][4] = {};
  for (int d = 0; d < 64; d += 2) {
    float da[4][2], db[4][2];
#pragma unroll
    for (int i = 0; i < 4; ++i) {
      float2 t = *reinterpret_cast<const float2*>(&eqs[ty * 4 + i][d]);
      da[i][0] = t.x; da[i][1] = t.y;
      float2 u = *reinterpret_cast<const float2*>(&eks[tx * 4 + i][d]);
      db[i][0] = u.x; db[i][1] = u.y;
    }
#pragma unroll
    for (int i = 0; i < 4; ++i)
#pragma unroll
      for (int j = 0; j < 4; ++j) {
        acc[i][j] = fmaf(da[i][0], db[j][0], acc[i][j]);   // d-ascending
        acc[i][j] = fmaf(da[i][1], db[j][1], acc[i][j]);
      }
  }

  float* po = pred + ((size_t)((bhc << 10) + rt * 64)) * 1024 + kt * 64;
#pragma unroll
  for (int i = 0; i < 4; ++i) {
    float4 o;
    o.x = acc[i][0]; o.y = acc[i][1]; o.z = acc[i][2]; o.w = acc[i][3];
    *reinterpret_cast<float4*>(&po[(size_t)(ty * 4 + i) * 1024 + tx * 4]) = o;
  }
}

// ---------------------------------------------------------------------------
// per row (1 wave): top-20 (value desc, index asc; cached-lane-max scan) ->
// sort asc -> logits: products staged to LDS, per-lane strict k-seq fold ->
// softmax (np-pairwise denom) -> probs bf16 + MX quant -> k-seq P.V ->
// fused output MX quant -> qout (bf16). Bit-identical numerics to r16.
// ---------------------------------------------------------------------------
__global__ __launch_bounds__(256) void topk_attn(const float* __restrict__ pred,
                                                 const ushort_t* __restrict__ qq,
                                                 const ushort_t* __restrict__ qk,
                                                 const ushort_t* __restrict__ qv,
                                                 ushort_t* __restrict__ qout,
                                                 int bh0) {
  __shared__ unsigned sidx[4][TOPK];
  __shared__ unsigned sj[4][TOPK];
  __shared__ __align__(16) float plds[4][TOPK][68];   // 68: 16B rows, low conflicts

  const int w = threadIdx.x >> 6, lane = threadIdx.x & 63;
  const int rl = blockIdx.x * 4 + w;
  const int bhc = rl >> 10, n = rl & 1023;
  const int bh = bh0 + bhc;
  const int b = bh / HEADS, h = bh - b * HEADS;

  const float* prow = pred + (size_t)rl * 1024;
  unsigned long long key[16];
#pragma unroll
  for (int t = 0; t < 16; ++t) {
    float v = prow[t * 64 + lane];
    key[t] = (((unsigned long long)ordf(v)) << 32) | (unsigned)(1023 - (t * 64 + lane));
  }

  // selection: cached per-lane max; same argmax sequence as full rescan
  unsigned long long lmax = key[0];
#pragma unroll
  for (int t = 1; t < 16; ++t) lmax = (key[t] > lmax) ? key[t] : lmax;
  for (int it = 0; it < TOPK; ++it) {
    unsigned long long m = lmax;
#pragma unroll
    for (int off = 32; off; off >>= 1) {
      unsigned long long o = __shfl_xor(m, off);
      m = (o > m) ? o : m;
    }
    if (lane == 0) sidx[w][it] = 1023u - (unsigned)(m & 0xffffffffu);
    if (lmax == m) {                 // unique owner lane
      unsigned long long nm = 0ull;
#pragma unroll
      for (int t = 0; t < 16; ++t) {
        key[t] = (key[t] == m) ? 0ull : key[t];
        nm = (key[t] > nm) ? key[t] : nm;
      }
      lmax = nm;
    }
  }

  // sort selected indices ascending (indices distinct)
  if (lane < TOPK) {
    unsigned myj0 = sidx[w][lane];
    int rank = 0;
    for (int k2 = 0; k2 < TOPK; ++k2) rank += (sidx[w][k2] < myj0) ? 1 : 0;
    sj[w][rank] = myj0;
  }

  // attn logits: per-lane products (exact f32 mul of bf16 values) staged to
  // LDS; lanes 0..19 fold their key's 64 products in strict k-ascending
  // order (adds only -> no contraction; order == r16's shfl fold).
  float qqv = bf2f(qq[((size_t)(bh << 10) + n) * 64 + lane]);
  for (int i = 0; i < TOPK; ++i) {
    unsigned j = sj[w][i];
    float p = qqv * bf2f(qk[((size_t)(bh << 10) + j) * 64 + lane]);
    plds[w][i][lane] = p;
  }
  __syncthreads();
  float attv = -__builtin_inff();
  if (lane < TOPK) {
    const float4* row4 = reinterpret_cast<const float4*>(&plds[w][lane][0]);
    float s = 0.f;
#pragma unroll
    for (int c = 0; c < 16; ++c) {
      float4 v4 = row4[c];
      s += v4.x; s += v4.y; s += v4.z; s += v4.w;   // k-ascending serial
    }
    attv = s * 0.125f;   // exact pow2 scale
  }

  // softmax max (exact)
  float mx = attv;
#pragma unroll
  for (int off = 32; off; off >>= 1) mx = fmaxf(mx, __shfl_xor(mx, off));
  float ev = (lane < TOPK) ? (float)exp((double)(attv - mx)) : 0.f;

  // np pairwise denominator over the virtual 1024-row: bucket (j>>7, j&7)
  float r = 0.f;
  {
    int Bk = lane >> 3, a = lane & 7;
    for (int i = 0; i < TOPK; ++i) {
      unsigned jj = sj[w][i];
      float evi = __shfl(ev, i);
      if ((int)(jj >> 7) == Bk && (int)(jj & 7) == a) r += evi;
    }
  }
#pragma unroll
  for (int off = 1; off < 64; off <<= 1) r += __shfl_xor(r, off);
  float denom = r;

  float pf = (lane < TOPK) ? (ev / denom) : 0.f;

  // bf16(probs) then MX quant along key axis (j>>5 blocks)
  float pb = bf16rne(pf);
  unsigned myj = (lane < TOPK) ? sj[w][lane] : 0xffffffffu;
  unsigned g = myj >> 5;
  float am = 0.f;
  for (int k2 = 0; k2 < TOPK; ++k2) {
    unsigned oj = __shfl(myj, k2);
    float ov = __shfl(pb, k2);
    if ((oj >> 5) == g) am = fmaxf(am, fabsf(ov));
  }
  int e = flog2(am > 0.f ? am : 1.f);
  float scale = ldexpf(1.f, e - 6);
  float qp = mxq(pb, scale);

  // P.V: k-seq ascending-index fold (lane = d; products exact)
  float o = 0.f;
  for (int i = 0; i < TOPK; ++i) {
    float wq = __shfl(qp, i);
    unsigned j = sj[w][i];
    o = fmaf(wq, bf2f(qv[((size_t)(bh << 10) + j) * 64 + lane]), o);
  }
  float xb2 = bf16rne(o);
  float am2 = fabsf(xb2);
#pragma unroll
  for (int off = 16; off; off >>= 1) am2 = fmaxf(am2, __shfl_xor(am2, off, 32));
  int e2 = flog2(am2 > 0.f ? am2 : 1.f);
  float sc2 = ldexpf(1.f, e2 - 6);
  qout[((size_t)((b << 10) + n)) * CDIM + h * 64 + lane] = f2bf(mxq(xb2, sc2));
}

// ---------------------------------------------------------------------------
// Host launcher
// ---------------------------------------------------------------------------
extern "C" void kernel_launch(void* const* d_in, const int* in_sizes, int n_in,
                              void* d_out, int out_size, void* d_ws, size_t ws_size,
                              hipStream_t stream) {
  (void)in_sizes; (void)n_in; (void)out_size;
  const float* x      = (const float*)d_in[0];
  const float* qkv_w  = (const float*)d_in[1];
  const float* qkv_b  = (const float*)d_in[2];
  const float* proj_w = (const float*)d_in[3];
  const float* proj_b = (const float*)d_in[4];
  float* out = (float*)d_out;

  size_t off = 0;
  auto alloc = [&](size_t bytes) -> void* {
    void* p = (char*)d_ws + off;
    off = (off + bytes + 255) & ~(size_t)255;
    return p;
  };
  ushort_t* qx   = (ushort_t*)alloc((size_t)ROWS * CDIM * 2);
  ushort_t* qw   = (ushort_t*)alloc((size_t)2304 * CDIM * 2);
  ushort_t* qq   = (ushort_t*)alloc((size_t)BHT * SEQ * DH * 2);
  ushort_t* qk   = (ushort_t*)alloc((size_t)BHT * SEQ * DH * 2);
  float*    eqr  = (float*)alloc((size_t)BHT * SEQ * DH * 4);
  float*    ekr  = (float*)alloc((size_t)BHT * SEQ * DH * 4);
  ushort_t* qv   = (ushort_t*)alloc((size_t)BHT * SEQ * DH * 2);
  ushort_t* qout = (ushort_t*)alloc((size_t)ROWS * CDIM * 2);
  ushort_t* qpw  = (ushort_t*)alloc((size_t)CDIM * CDIM * 2);
  float*    qkv  = (float*)alloc((size_t)ROWS * 2304 * 4);

  const size_t per_bh = (size_t)SEQ * SEQ * 4;
  static const int divs[] = {48, 24, 16, 12, 8, 6, 4, 3, 2, 1};
  int CB = 1;
  for (int i = 0; i < 10; ++i)
    if (off + (size_t)divs[i] * per_bh + 256 <= ws_size) { CB = divs[i]; break; }
  float* pred = (float*)alloc((size_t)CB * per_bh);

  // 1) MX quantize inputs
  quant_rows<<<(ROWS * CDIM) / 256, 256, 0, stream>>>(x, qx);
  quant_rows<<<(2304 * CDIM) / 256, 256, 0, stream>>>(qkv_w, qw);
  quant_rows<<<(CDIM * CDIM) / 256, 256, 0, stream>>>(proj_w, qpw);

  // 2) qkv = f32 k-seq(qx @ qw^T) + bias, then per-head builds
  gemm_f32_bt<<<dim3(2304 / 128, ROWS / 64), 256, 0, stream>>>(
      qx, qw, qkv_b, qkv, ROWS, 2304, CDIM);
  build_qke<<<(2 * ROWS * CDIM) / 256, 256, 0, stream>>>(qkv, qq, qk, eqr, ekr);
  build_qv<<<BHT * 32, 64, 0, stream>>>(qkv, qv);

  // 3) chunked: pred + fused topk/attn/softmax/PV/out-quant
  for (int bh0 = 0; bh0 < BHT; bh0 += CB) {
    pred_kernel<<<dim3(16, 16, CB), 256, 0, stream>>>(eqr, ekr, pred, bh0);
    topk_attn<<<CB * (SEQ / 4), 256, 0, stream>>>(pred, qq, qk, qv, qout, bh0);
  }

  // 4) final projection (f32 MFMA — no discrete decisions downstream)
  gemm_bt<<<dim3(CDIM / 64, ROWS / 64), 256, 0, stream>>>(qout, qpw, proj_b, out,
                                                          ROWS, CDIM, CDIM);
}

// Round 19
// 757.690 us; speedup vs baseline: 1.8265x; 1.2025x over previous
//
#include <hip/hip_runtime.h>
#include <hip/hip_bf16.h>
#include <cstdint>
#include <cstddef>

// ---------------------------------------------------------------------------
// QuantizedAttention (MX int8 block quant, exponent-sign top-k mask)
// B=4 N=1024 C=768 H=12 Dh=64 TOPK=20 BLOCK=32
// PASSING semantics (r16/r17), decision-path numerics preserved BIT-EXACTLY:
//   - exponent_sign = jax-faithful log2: f32(log(f64 x)) / fl32(ln2), floor.
//     eq from 0.125f*q, ek raw. bf16 = RNE. top-k (value desc, index asc).
//     k-seq BLAS sums; np-pairwise softmax denominator; CR exp (f64->f32).
// r19 = r18 with the ushort8 typedef fixed: gemm_f32_bt stores f32 in LDS
// (bf16->f32 converted once during staging; <<16 exact -> identical fmaf
// chain -> bit-identical output). Stride-36 f32 rows: 16B aligned.
// ---------------------------------------------------------------------------

typedef __attribute__((ext_vector_type(8))) short short8;
typedef __attribute__((ext_vector_type(8))) unsigned short ushort8;
typedef __attribute__((ext_vector_type(4))) float f32x4;
typedef unsigned short ushort_t;

#define DEV static __device__ __forceinline__

constexpr int BATCH = 4, SEQ = 1024, CDIM = 768, HEADS = 12, DH = 64;
constexpr int ROWS = BATCH * SEQ;          // 4096
constexpr int BHT = BATCH * HEADS;         // 48
constexpr int TOPK = 20;

DEV float bf16rne(float x) {
  unsigned u = __float_as_uint(x);
  u += 0x7fffu + ((u >> 16) & 1u);
  return __uint_as_float(u & 0xffff0000u);
}
DEV ushort_t f2bf(float x) {
  unsigned u = __float_as_uint(x);
  u += 0x7fffu + ((u >> 16) & 1u);
  return (ushort_t)(u >> 16);
}
DEV float bf2f(ushort_t b) { return __uint_as_float(((unsigned)b) << 16); }
// exact floor(log2) — used for MX shared_exp (bf16-valued amax, robust)
DEV int flog2(float ax) { int e; (void)frexpf(ax, &e); return e - 1; }
DEV float mxq(float xb, float scale) {
  float q = rintf(xb / scale);              // round half to even; /pow2 exact
  q = fminf(fmaxf(q, -127.f), 127.f);
  return q * scale;
}
DEV unsigned ordf(float p) {
  if (p == 0.f) return 0x80000000u;
  unsigned u = __float_as_uint(p);
  return (u & 0x80000000u) ? ~u : (u | 0x80000000u);
}

// jax-faithful log2: f32 CR log divided by f32 log(2) constant
DEV float esig_jax(float v) {
  float ax = fabsf(v);
  if (!(ax > 0.f)) return 0.f;
  float lg = (float)log((double)ax);                 // ~CR f32 log
  float l2 = lg / 0.69314718246459960938f;           // f32 division by fl(ln2)
  float fl = floorf(l2);
  return copysignf(exp2f(fl), v);                    // exp2 of integer: exact
}

// ---------------------------------------------------------------------------
// mx_quant(bf16_quant(x), axis=-1) for row-major [R, C], C % 32 == 0.
// ---------------------------------------------------------------------------
__global__ __launch_bounds__(256) void quant_rows(const float* __restrict__ in,
                                                  ushort_t* __restrict__ out) {
  int gid = blockIdx.x * 256 + threadIdx.x;
  float xb = bf16rne(in[gid]);
  float a = fabsf(xb);
#pragma unroll
  for (int off = 16; off; off >>= 1) a = fmaxf(a, __shfl_xor(a, off, 32));
  int e = flog2(a > 0.f ? a : 1.f);
  float scale = ldexpf(1.f, e - 6);
  out[gid] = f2bf(mxq(xb, scale));
}

// ---------------------------------------------------------------------------
// k-sequential f32 GEMM (BLAS model): C = f32seq(A[M,K]*B[N,K]^T) + bias
// 64x128 tile, 256 threads, 4x8 outputs/thread. f32 LDS (converted during
// staging). Per-output: single f32 accumulator, strict k-ascending fmaf —
// bit-identical to r16/r17. Requires N % 128 == 0, K % 32 == 0.
// ---------------------------------------------------------------------------
__global__ __launch_bounds__(256) void gemm_f32_bt(const ushort_t* __restrict__ A,
                                                   const ushort_t* __restrict__ Bm,
                                                   const float* __restrict__ bias,
                                                   float* __restrict__ C,
                                                   int M, int N, int K) {
  constexpr int LS = 36;   // f32 stride: 144B rows -> 16B aligned
  __shared__ __align__(16) float As[64][LS];
  __shared__ __align__(16) float Bs[128][LS];
  const int tid = threadIdx.x;
  const int ty = tid >> 4, tx = tid & 15;
  const int m0 = blockIdx.y * 64, n0 = blockIdx.x * 128;
  float acc[4][8] = {};
  const int sr = tid >> 2, sc = (tid & 3) * 8;   // A staging: 8 elems/thread
  const int br = tid >> 1, bc = (tid & 1) * 16;  // B staging: 16 elems/thread

  for (int k0 = 0; k0 < K; k0 += 32) {
    {
      ushort8 a8 = *reinterpret_cast<const ushort8*>(
          A + (size_t)(m0 + sr) * K + k0 + sc);
      float4 f0, f1;
      f0.x = bf2f(a8.s0); f0.y = bf2f(a8.s1); f0.z = bf2f(a8.s2); f0.w = bf2f(a8.s3);
      f1.x = bf2f(a8.s4); f1.y = bf2f(a8.s5); f1.z = bf2f(a8.s6); f1.w = bf2f(a8.s7);
      *reinterpret_cast<float4*>(&As[sr][sc])     = f0;
      *reinterpret_cast<float4*>(&As[sr][sc + 4]) = f1;
    }
    {
      const ushort_t* bg = Bm + (size_t)(n0 + br) * K + k0 + bc;
      ushort8 b8a = *reinterpret_cast<const ushort8*>(bg);
      ushort8 b8b = *reinterpret_cast<const ushort8*>(bg + 8);
      float4 g0, g1, g2, g3;
      g0.x = bf2f(b8a.s0); g0.y = bf2f(b8a.s1); g0.z = bf2f(b8a.s2); g0.w = bf2f(b8a.s3);
      g1.x = bf2f(b8a.s4); g1.y = bf2f(b8a.s5); g1.z = bf2f(b8a.s6); g1.w = bf2f(b8a.s7);
      g2.x = bf2f(b8b.s0); g2.y = bf2f(b8b.s1); g2.z = bf2f(b8b.s2); g2.w = bf2f(b8b.s3);
      g3.x = bf2f(b8b.s4); g3.y = bf2f(b8b.s5); g3.z = bf2f(b8b.s6); g3.w = bf2f(b8b.s7);
      *reinterpret_cast<float4*>(&Bs[br][bc])      = g0;
      *reinterpret_cast<float4*>(&Bs[br][bc + 4])  = g1;
      *reinterpret_cast<float4*>(&Bs[br][bc + 8])  = g2;
      *reinterpret_cast<float4*>(&Bs[br][bc + 12]) = g3;
    }
    __syncthreads();
#pragma unroll
    for (int kk = 0; kk < 32; kk += 4) {
      float4 a4[4], b4[8];
#pragma unroll
      for (int i = 0; i < 4; ++i)
        a4[i] = *reinterpret_cast<const float4*>(&As[ty * 4 + i][kk]);
#pragma unroll
      for (int j = 0; j < 8; ++j)
        b4[j] = *reinterpret_cast<const float4*>(&Bs[j * 16 + tx][kk]);
#pragma unroll
      for (int i = 0; i < 4; ++i)
#pragma unroll
        for (int j = 0; j < 8; ++j) {
          acc[i][j] = fmaf(a4[i].x, b4[j].x, acc[i][j]);   // k-ascending
          acc[i][j] = fmaf(a4[i].y, b4[j].y, acc[i][j]);
          acc[i][j] = fmaf(a4[i].z, b4[j].z, acc[i][j]);
          acc[i][j] = fmaf(a4[i].w, b4[j].w, acc[i][j]);
        }
    }
    __syncthreads();
  }
#pragma unroll
  for (int i = 0; i < 4; ++i)
#pragma unroll
    for (int j = 0; j < 8; ++j) {
      int row = m0 + ty * 4 + i, col = n0 + j * 16 + tx;
      C[(size_t)row * N + col] = acc[i][j] + bias[col];
    }
}

// ---------------------------------------------------------------------------
// bf16 MFMA GEMM (f32 accumulate) — final projection only.
// ---------------------------------------------------------------------------
__global__ __launch_bounds__(256) void gemm_bt(const ushort_t* __restrict__ A,
                                               const ushort_t* __restrict__ Bm,
                                               const float* __restrict__ bias,
                                               float* __restrict__ C,
                                               int M, int N, int K) {
  constexpr int KS = 40;
  __shared__ ushort_t As[64][KS];
  __shared__ ushort_t Bs[64][KS];
  const int tid = threadIdx.x;
  const int w = tid >> 6, lane = tid & 63;
  const int wm = w >> 1, wn = w & 1;
  const int m0 = blockIdx.y * 64, n0 = blockIdx.x * 64;

  f32x4 acc[2][2];
#pragma unroll
  for (int i = 0; i < 2; ++i)
#pragma unroll
    for (int j = 0; j < 2; ++j) acc[i][j] = (f32x4){0.f, 0.f, 0.f, 0.f};

  const int sr = tid >> 2, sc = (tid & 3) * 8;
  for (int k0 = 0; k0 < K; k0 += 32) {
    *reinterpret_cast<uint4*>(&As[sr][sc]) =
        *reinterpret_cast<const uint4*>(A + (size_t)(m0 + sr) * K + k0 + sc);
    *reinterpret_cast<uint4*>(&Bs[sr][sc]) =
        *reinterpret_cast<const uint4*>(Bm + (size_t)(n0 + sr) * K + k0 + sc);
    __syncthreads();
    const int fr = lane & 15, koff = (lane >> 4) * 8;
    short8 av[2], bv[2];
#pragma unroll
    for (int f = 0; f < 2; ++f) {
      av[f] = *reinterpret_cast<const short8*>(&As[wm * 32 + f * 16 + fr][koff]);
      bv[f] = *reinterpret_cast<const short8*>(&Bs[wn * 32 + f * 16 + fr][koff]);
    }
#pragma unroll
    for (int fm = 0; fm < 2; ++fm)
#pragma unroll
      for (int fn = 0; fn < 2; ++fn)
        acc[fm][fn] = __builtin_amdgcn_mfma_f32_16x16x32_bf16(av[fm], bv[fn], acc[fm][fn], 0, 0, 0);
    __syncthreads();
  }
  const int cl = lane & 15, rq = (lane >> 4) * 4;
#pragma unroll
  for (int fm = 0; fm < 2; ++fm)
#pragma unroll
    for (int fn = 0; fn < 2; ++fn) {
      int col = n0 + wn * 32 + fn * 16 + cl;
      float bb = bias[col];
#pragma unroll
      for (int j = 0; j < 4; ++j) {
        int row = m0 + wm * 32 + fm * 16 + rq + j;
        C[(size_t)row * N + col] = acc[fm][fn][j] + bb;
      }
    }
}

// ---------------------------------------------------------------------------
// build q/k per-head quantized bf16 + exponent-sign arrays from f32 qkv.
// eq = esig_jax(0.125f * q); ek = esig_jax(k).
// ---------------------------------------------------------------------------
__global__ __launch_bounds__(256) void build_qke(const float* __restrict__ qkv,
                                                 ushort_t* __restrict__ qq,
                                                 ushort_t* __restrict__ qk,
                                                 float* __restrict__ eqr,
                                                 float* __restrict__ ekr) {
  const int HALF = ROWS * CDIM;
  int gid = blockIdx.x * 256 + threadIdx.x;
  int s = (gid >= HALF) ? 1 : 0;
  int rem = gid - s * HALF;
  int row = rem / CDIM, c = rem % CDIM;
  float v = qkv[(size_t)row * 2304 + s * CDIM + c];

  float es = esig_jax(s == 0 ? 0.125f * v : v);
  float xb = bf16rne(v);
  float a = fabsf(xb);
#pragma unroll
  for (int off = 16; off; off >>= 1) a = fmaxf(a, __shfl_xor(a, off, 32));
  int e = flog2(a > 0.f ? a : 1.f);
  float scale = ldexpf(1.f, e - 6);
  ushort_t qb = f2bf(mxq(xb, scale));

  int h = c >> 6, d = c & 63, b = row >> 10, n = row & 1023;
  size_t dst = ((size_t)((b * HEADS + h) << 10) + n) * 64 + d;
  if (s == 0) { qq[dst] = qb; eqr[dst] = es; }
  else        { qk[dst] = qb; ekr[dst] = es; }
}

// ---------------------------------------------------------------------------
// v quantized along N (axis=-2): per (bh, d) column, 32-row blocks.
// ---------------------------------------------------------------------------
__global__ __launch_bounds__(64) void build_qv(const float* __restrict__ qkv,
                                               ushort_t* __restrict__ qv) {
  int bh = blockIdx.x >> 5, nb = blockIdx.x & 31;
  int b = bh / HEADS, h = bh - b * HEADS;
  int d = threadIdx.x;
  float xs[32];
  float am = 0.f;
#pragma unroll
  for (int i = 0; i < 32; ++i) {
    int n = nb * 32 + i;
    float xb = bf16rne(qkv[(size_t)((b << 10) + n) * 2304 + 1536 + h * 64 + d]);
    xs[i] = xb;
    am = fmaxf(am, fabsf(xb));
  }
  int e = flog2(am > 0.f ? am : 1.f);
  float scale = ldexpf(1.f, e - 6);
#pragma unroll
  for (int i = 0; i < 32; ++i)
    qv[((size_t)(bh << 10) + nb * 32 + i) * 64 + d] = f2bf(mxq(xs[i], scale));
}

// ---------------------------------------------------------------------------
// pred[bhc, r, j] = f32 k-seq( eq[r,:] * ek[j,:] )
// ---------------------------------------------------------------------------
__global__ __launch_bounds__(256) void pred_kernel(const float* __restrict__ eqr,
                                                   const float* __restrict__ ekr,
                                                   float* __restrict__ pred,
                                                   int bh0) {
  constexpr int LS = 66;
  __shared__ float eqs[64][LS];
  __shared__ float eks[64][LS];
  int bhc = blockIdx.z, bh = bh0 + bhc;
  int rt = blockIdx.y, kt = blockIdx.x;
  int tid = threadIdx.x;

  const float* eqg = eqr + ((size_t)bh << 16) + (size_t)rt * 64 * 64;
  const float* ekg = ekr + ((size_t)bh << 16) + (size_t)kt * 64 * 64;
#pragma unroll
  for (int it = 0; it < 16; ++it) {
    int flat = it * 256 + tid;
    int r = flat >> 6, d = flat & 63;
    eqs[r][d] = eqg[flat];
    eks[r][d] = ekg[flat];
  }
  __syncthreads();

  int ty = tid >> 4, tx = tid & 15;
  float acc[4][4] = {};
  for (int d = 0; d < 64; d += 2) {
    float da[4][2], db[4][2];
#pragma unroll
    for (int i = 0; i < 4; ++i) {
      float2 t = *reinterpret_cast<const float2*>(&eqs[ty * 4 + i][d]);
      da[i][0] = t.x; da[i][1] = t.y;
      float2 u = *reinterpret_cast<const float2*>(&eks[tx * 4 + i][d]);
      db[i][0] = u.x; db[i][1] = u.y;
    }
#pragma unroll
    for (int i = 0; i < 4; ++i)
#pragma unroll
      for (int j = 0; j < 4; ++j) {
        acc[i][j] = fmaf(da[i][0], db[j][0], acc[i][j]);   // d-ascending
        acc[i][j] = fmaf(da[i][1], db[j][1], acc[i][j]);
      }
  }

  float* po = pred + ((size_t)((bhc << 10) + rt * 64)) * 1024 + kt * 64;
#pragma unroll
  for (int i = 0; i < 4; ++i) {
    float4 o;
    o.x = acc[i][0]; o.y = acc[i][1]; o.z = acc[i][2]; o.w = acc[i][3];
    *reinterpret_cast<float4*>(&po[(size_t)(ty * 4 + i) * 1024 + tx * 4]) = o;
  }
}

// ---------------------------------------------------------------------------
// per row (1 wave): top-20 (value desc, index asc; cached-lane-max scan) ->
// sort asc -> logits: products staged to LDS, per-lane strict k-seq fold ->
// softmax (np-pairwise denom) -> probs bf16 + MX quant -> k-seq P.V ->
// fused output MX quant -> qout (bf16).
// ---------------------------------------------------------------------------
__global__ __launch_bounds__(256) void topk_attn(const float* __restrict__ pred,
                                                 const ushort_t* __restrict__ qq,
                                                 const ushort_t* __restrict__ qk,
                                                 const ushort_t* __restrict__ qv,
                                                 ushort_t* __restrict__ qout,
                                                 int bh0) {
  __shared__ unsigned sidx[4][TOPK];
  __shared__ unsigned sj[4][TOPK];
  __shared__ __align__(16) float plds[4][TOPK][68];

  const int w = threadIdx.x >> 6, lane = threadIdx.x & 63;
  const int rl = blockIdx.x * 4 + w;
  const int bhc = rl >> 10, n = rl & 1023;
  const int bh = bh0 + bhc;
  const int b = bh / HEADS, h = bh - b * HEADS;

  const float* prow = pred + (size_t)rl * 1024;
  unsigned long long key[16];
#pragma unroll
  for (int t = 0; t < 16; ++t) {
    float v = prow[t * 64 + lane];
    key[t] = (((unsigned long long)ordf(v)) << 32) | (unsigned)(1023 - (t * 64 + lane));
  }

  // selection: cached per-lane max; same argmax sequence as full rescan
  unsigned long long lmax = key[0];
#pragma unroll
  for (int t = 1; t < 16; ++t) lmax = (key[t] > lmax) ? key[t] : lmax;
  for (int it = 0; it < TOPK; ++it) {
    unsigned long long m = lmax;
#pragma unroll
    for (int off = 32; off; off >>= 1) {
      unsigned long long o = __shfl_xor(m, off);
      m = (o > m) ? o : m;
    }
    if (lane == 0) sidx[w][it] = 1023u - (unsigned)(m & 0xffffffffu);
    if (lmax == m) {                 // unique owner lane
      unsigned long long nm = 0ull;
#pragma unroll
      for (int t = 0; t < 16; ++t) {
        key[t] = (key[t] == m) ? 0ull : key[t];
        nm = (key[t] > nm) ? key[t] : nm;
      }
      lmax = nm;
    }
  }

  // sort selected indices ascending (indices distinct)
  if (lane < TOPK) {
    unsigned myj0 = sidx[w][lane];
    int rank = 0;
    for (int k2 = 0; k2 < TOPK; ++k2) rank += (sidx[w][k2] < myj0) ? 1 : 0;
    sj[w][rank] = myj0;
  }

  // attn logits: per-lane products staged to LDS; lanes 0..19 fold their
  // key's 64 products in strict k-ascending order.
  float qqv = bf2f(qq[((size_t)(bh << 10) + n) * 64 + lane]);
  for (int i = 0; i < TOPK; ++i) {
    unsigned j = sj[w][i];
    float p = qqv * bf2f(qk[((size_t)(bh << 10) + j) * 64 + lane]);
    plds[w][i][lane] = p;
  }
  __syncthreads();
  float attv = -__builtin_inff();
  if (lane < TOPK) {
    const float4* row4 = reinterpret_cast<const float4*>(&plds[w][lane][0]);
    float s = 0.f;
#pragma unroll
    for (int c = 0; c < 16; ++c) {
      float4 v4 = row4[c];
      s += v4.x; s += v4.y; s += v4.z; s += v4.w;   // k-ascending serial
    }
    attv = s * 0.125f;   // exact pow2 scale
  }

  // softmax max (exact)
  float mx = attv;
#pragma unroll
  for (int off = 32; off; off >>= 1) mx = fmaxf(mx, __shfl_xor(mx, off));
  float ev = (lane < TOPK) ? (float)exp((double)(attv - mx)) : 0.f;

  // np pairwise denominator over the virtual 1024-row: bucket (j>>7, j&7)
  float r = 0.f;
  {
    int Bk = lane >> 3, a = lane & 7;
    for (int i = 0; i < TOPK; ++i) {
      unsigned jj = sj[w][i];
      float evi = __shfl(ev, i);
      if ((int)(jj >> 7) == Bk && (int)(jj & 7) == a) r += evi;
    }
  }
#pragma unroll
  for (int off = 1; off < 64; off <<= 1) r += __shfl_xor(r, off);
  float denom = r;

  float pf = (lane < TOPK) ? (ev / denom) : 0.f;

  // bf16(probs) then MX quant along key axis (j>>5 blocks)
  float pb = bf16rne(pf);
  unsigned myj = (lane < TOPK) ? sj[w][lane] : 0xffffffffu;
  unsigned g = myj >> 5;
  float am = 0.f;
  for (int k2 = 0; k2 < TOPK; ++k2) {
    unsigned oj = __shfl(myj, k2);
    float ov = __shfl(pb, k2);
    if ((oj >> 5) == g) am = fmaxf(am, fabsf(ov));
  }
  int e = flog2(am > 0.f ? am : 1.f);
  float scale = ldexpf(1.f, e - 6);
  float qp = mxq(pb, scale);

  // P.V: k-seq ascending-index fold (lane = d; products exact)
  float o = 0.f;
  for (int i = 0; i < TOPK; ++i) {
    float wq = __shfl(qp, i);
    unsigned j = sj[w][i];
    o = fmaf(wq, bf2f(qv[((size_t)(bh << 10) + j) * 64 + lane]), o);
  }
  float xb2 = bf16rne(o);
  float am2 = fabsf(xb2);
#pragma unroll
  for (int off = 16; off; off >>= 1) am2 = fmaxf(am2, __shfl_xor(am2, off, 32));
  int e2 = flog2(am2 > 0.f ? am2 : 1.f);
  float sc2 = ldexpf(1.f, e2 - 6);
  qout[((size_t)((b << 10) + n)) * CDIM + h * 64 + lane] = f2bf(mxq(xb2, sc2));
}

// ---------------------------------------------------------------------------
// Host launcher
// ---------------------------------------------------------------------------
extern "C" void kernel_launch(void* const* d_in, const int* in_sizes, int n_in,
                              void* d_out, int out_size, void* d_ws, size_t ws_size,
                              hipStream_t stream) {
  (void)in_sizes; (void)n_in; (void)out_size;
  const float* x      = (const float*)d_in[0];
  const float* qkv_w  = (const float*)d_in[1];
  const float* qkv_b  = (const float*)d_in[2];
  const float* proj_w = (const float*)d_in[3];
  const float* proj_b = (const float*)d_in[4];
  float* out = (float*)d_out;

  size_t off = 0;
  auto alloc = [&](size_t bytes) -> void* {
    void* p = (char*)d_ws + off;
    off = (off + bytes + 255) & ~(size_t)255;
    return p;
  };
  ushort_t* qx   = (ushort_t*)alloc((size_t)ROWS * CDIM * 2);
  ushort_t* qw   = (ushort_t*)alloc((size_t)2304 * CDIM * 2);
  ushort_t* qq   = (ushort_t*)alloc((size_t)BHT * SEQ * DH * 2);
  ushort_t* qk   = (ushort_t*)alloc((size_t)BHT * SEQ * DH * 2);
  float*    eqr  = (float*)alloc((size_t)BHT * SEQ * DH * 4);
  float*    ekr  = (float*)alloc((size_t)BHT * SEQ * DH * 4);
  ushort_t* qv   = (ushort_t*)alloc((size_t)BHT * SEQ * DH * 2);
  ushort_t* qout = (ushort_t*)alloc((size_t)ROWS * CDIM * 2);
  ushort_t* qpw  = (ushort_t*)alloc((size_t)CDIM * CDIM * 2);
  float*    qkv  = (float*)alloc((size_t)ROWS * 2304 * 4);

  const size_t per_bh = (size_t)SEQ * SEQ * 4;
  static const int divs[] = {48, 24, 16, 12, 8, 6, 4, 3, 2, 1};
  int CB = 1;
  for (int i = 0; i < 10; ++i)
    if (off + (size_t)divs[i] * per_bh + 256 <= ws_size) { CB = divs[i]; break; }
  float* pred = (float*)alloc((size_t)CB * per_bh);

  // 1) MX quantize inputs
  quant_rows<<<(ROWS * CDIM) / 256, 256, 0, stream>>>(x, qx);
  quant_rows<<<(2304 * CDIM) / 256, 256, 0, stream>>>(qkv_w, qw);
  quant_rows<<<(CDIM * CDIM) / 256, 256, 0, stream>>>(proj_w, qpw);

  // 2) qkv = f32 k-seq(qx @ qw^T) + bias, then per-head builds
  gemm_f32_bt<<<dim3(2304 / 128, ROWS / 64), 256, 0, stream>>>(
      qx, qw, qkv_b, qkv, ROWS, 2304, CDIM);
  build_qke<<<(2 * ROWS * CDIM) / 256, 256, 0, stream>>>(qkv, qq, qk, eqr, ekr);
  build_qv<<<BHT * 32, 64, 0, stream>>>(qkv, qv);

  // 3) chunked: pred + fused topk/attn/softmax/PV/out-quant
  for (int bh0 = 0; bh0 < BHT; bh0 += CB) {
    pred_kernel<<<dim3(16, 16, CB), 256, 0, stream>>>(eqr, ekr, pred, bh0);
    topk_attn<<<CB * (SEQ / 4), 256, 0, stream>>>(pred, qq, qk, qv, qout, bh0);
  }

  // 4) final projection (f32 MFMA — no discrete decisions downstream)
  gemm_bt<<<dim3(CDIM / 64, ROWS / 64), 256, 0, stream>>>(qout, qpw, proj_b, out,
                                                          ROWS, CDIM, CDIM);
}

// Round 20
// 734.354 us; speedup vs baseline: 1.8845x; 1.0318x over previous
//
#include <hip/hip_runtime.h>
#include <hip/hip_bf16.h>
#include <cstdint>
#include <cstddef>

// ---------------------------------------------------------------------------
// QuantizedAttention (MX int8 block quant, exponent-sign top-k mask)
// B=4 N=1024 C=768 H=12 Dh=64 TOPK=20 BLOCK=32
// PASSING semantics (r16+), decision-path numerics preserved BIT-EXACTLY:
//   - exponent_sign = jax-faithful log2: f32(log(f64 x)) / fl32(ln2), floor.
//     eq from 0.125f*q, ek raw. bf16 = RNE. top-k (value desc, index asc).
//     k-seq BLAS sums; np-pairwise softmax denominator; CR exp (f64->f32).
// r20 = performance only: gemm_f32_bt re-tiled to 128x128, 8x8 per thread,
// A-rows = ty + 16*i (conflict-free A-read quads). Per-output accumulator
// chain unchanged (strict k-ascending fmaf) -> bit-identical qkv.
// ---------------------------------------------------------------------------

typedef __attribute__((ext_vector_type(8))) short short8;
typedef __attribute__((ext_vector_type(8))) unsigned short ushort8;
typedef __attribute__((ext_vector_type(4))) float f32x4;
typedef unsigned short ushort_t;

#define DEV static __device__ __forceinline__

constexpr int BATCH = 4, SEQ = 1024, CDIM = 768, HEADS = 12, DH = 64;
constexpr int ROWS = BATCH * SEQ;          // 4096
constexpr int BHT = BATCH * HEADS;         // 48
constexpr int TOPK = 20;

DEV float bf16rne(float x) {
  unsigned u = __float_as_uint(x);
  u += 0x7fffu + ((u >> 16) & 1u);
  return __uint_as_float(u & 0xffff0000u);
}
DEV ushort_t f2bf(float x) {
  unsigned u = __float_as_uint(x);
  u += 0x7fffu + ((u >> 16) & 1u);
  return (ushort_t)(u >> 16);
}
DEV float bf2f(ushort_t b) { return __uint_as_float(((unsigned)b) << 16); }
// exact floor(log2) — used for MX shared_exp (bf16-valued amax, robust)
DEV int flog2(float ax) { int e; (void)frexpf(ax, &e); return e - 1; }
DEV float mxq(float xb, float scale) {
  float q = rintf(xb / scale);              // round half to even; /pow2 exact
  q = fminf(fmaxf(q, -127.f), 127.f);
  return q * scale;
}
DEV unsigned ordf(float p) {
  if (p == 0.f) return 0x80000000u;
  unsigned u = __float_as_uint(p);
  return (u & 0x80000000u) ? ~u : (u | 0x80000000u);
}

// jax-faithful log2: f32 CR log divided by f32 log(2) constant
DEV float esig_jax(float v) {
  float ax = fabsf(v);
  if (!(ax > 0.f)) return 0.f;
  float lg = (float)log((double)ax);                 // ~CR f32 log
  float l2 = lg / 0.69314718246459960938f;           // f32 division by fl(ln2)
  float fl = floorf(l2);
  return copysignf(exp2f(fl), v);                    // exp2 of integer: exact
}

// ---------------------------------------------------------------------------
// mx_quant(bf16_quant(x), axis=-1) for row-major [R, C], C % 32 == 0.
// ---------------------------------------------------------------------------
__global__ __launch_bounds__(256) void quant_rows(const float* __restrict__ in,
                                                  ushort_t* __restrict__ out) {
  int gid = blockIdx.x * 256 + threadIdx.x;
  float xb = bf16rne(in[gid]);
  float a = fabsf(xb);
#pragma unroll
  for (int off = 16; off; off >>= 1) a = fmaxf(a, __shfl_xor(a, off, 32));
  int e = flog2(a > 0.f ? a : 1.f);
  float scale = ldexpf(1.f, e - 6);
  out[gid] = f2bf(mxq(xb, scale));
}

// ---------------------------------------------------------------------------
// k-sequential f32 GEMM (BLAS model): C = f32seq(A[M,K]*B[N,K]^T) + bias
// 128x128 tile, 256 threads, 8x8 outputs/thread; A-rows = ty + 16*i
// (conflict-free A-read bank quads). f32 LDS, converted during staging.
// Per-output: single f32 accumulator, strict k-ascending fmaf —
// bit-identical to r16-r19. Requires M,N % 128 == 0, K % 32 == 0.
// ---------------------------------------------------------------------------
__global__ __launch_bounds__(256) void gemm_f32_bt(const ushort_t* __restrict__ A,
                                                   const ushort_t* __restrict__ Bm,
                                                   const float* __restrict__ bias,
                                                   float* __restrict__ C,
                                                   int M, int N, int K) {
  constexpr int LS = 36;   // f32 stride: 144B rows -> 16B aligned
  __shared__ __align__(16) float As[128][LS];
  __shared__ __align__(16) float Bs[128][LS];
  const int tid = threadIdx.x;
  const int ty = tid >> 4, tx = tid & 15;
  const int m0 = blockIdx.y * 128, n0 = blockIdx.x * 128;
  float acc[8][8] = {};
  const int sr = tid >> 1, sc = (tid & 1) * 16;  // staging: 16 elems/thread

  for (int k0 = 0; k0 < K; k0 += 32) {
    {
      const ushort_t* ag = A + (size_t)(m0 + sr) * K + k0 + sc;
      ushort8 a8a = *reinterpret_cast<const ushort8*>(ag);
      ushort8 a8b = *reinterpret_cast<const ushort8*>(ag + 8);
      float4 f0, f1, f2, f3;
      f0.x = bf2f(a8a.s0); f0.y = bf2f(a8a.s1); f0.z = bf2f(a8a.s2); f0.w = bf2f(a8a.s3);
      f1.x = bf2f(a8a.s4); f1.y = bf2f(a8a.s5); f1.z = bf2f(a8a.s6); f1.w = bf2f(a8a.s7);
      f2.x = bf2f(a8b.s0); f2.y = bf2f(a8b.s1); f2.z = bf2f(a8b.s2); f2.w = bf2f(a8b.s3);
      f3.x = bf2f(a8b.s4); f3.y = bf2f(a8b.s5); f3.z = bf2f(a8b.s6); f3.w = bf2f(a8b.s7);
      *reinterpret_cast<float4*>(&As[sr][sc])      = f0;
      *reinterpret_cast<float4*>(&As[sr][sc + 4])  = f1;
      *reinterpret_cast<float4*>(&As[sr][sc + 8])  = f2;
      *reinterpret_cast<float4*>(&As[sr][sc + 12]) = f3;
    }
    {
      const ushort_t* bg = Bm + (size_t)(n0 + sr) * K + k0 + sc;
      ushort8 b8a = *reinterpret_cast<const ushort8*>(bg);
      ushort8 b8b = *reinterpret_cast<const ushort8*>(bg + 8);
      float4 g0, g1, g2, g3;
      g0.x = bf2f(b8a.s0); g0.y = bf2f(b8a.s1); g0.z = bf2f(b8a.s2); g0.w = bf2f(b8a.s3);
      g1.x = bf2f(b8a.s4); g1.y = bf2f(b8a.s5); g1.z = bf2f(b8a.s6); g1.w = bf2f(b8a.s7);
      g2.x = bf2f(b8b.s0); g2.y = bf2f(b8b.s1); g2.z = bf2f(b8b.s2); g2.w = bf2f(b8b.s3);
      g3.x = bf2f(b8b.s4); g3.y = bf2f(b8b.s5); g3.z = bf2f(b8b.s6); g3.w = bf2f(b8b.s7);
      *reinterpret_cast<float4*>(&Bs[sr][sc])      = g0;
      *reinterpret_cast<float4*>(&Bs[sr][sc + 4])  = g1;
      *reinterpret_cast<float4*>(&Bs[sr][sc + 8])  = g2;
      *reinterpret_cast<float4*>(&Bs[sr][sc + 12]) = g3;
    }
    __syncthreads();
#pragma unroll
    for (int kk = 0; kk < 32; kk += 4) {
      float4 a4[8];
#pragma unroll
      for (int i = 0; i < 8; ++i)
        a4[i] = *reinterpret_cast<const float4*>(&As[ty + 16 * i][kk]);
#pragma unroll
      for (int j = 0; j < 8; ++j) {
        float4 b4 = *reinterpret_cast<const float4*>(&Bs[j * 16 + tx][kk]);
#pragma unroll
        for (int i = 0; i < 8; ++i) {
          acc[i][j] = fmaf(a4[i].x, b4.x, acc[i][j]);   // k-ascending
          acc[i][j] = fmaf(a4[i].y, b4.y, acc[i][j]);
          acc[i][j] = fmaf(a4[i].z, b4.z, acc[i][j]);
          acc[i][j] = fmaf(a4[i].w, b4.w, acc[i][j]);
        }
      }
    }
    __syncthreads();
  }
#pragma unroll
  for (int i = 0; i < 8; ++i)
#pragma unroll
    for (int j = 0; j < 8; ++j) {
      int row = m0 + ty + 16 * i, col = n0 + j * 16 + tx;
      C[(size_t)row * N + col] = acc[i][j] + bias[col];
    }
}

// ---------------------------------------------------------------------------
// bf16 MFMA GEMM (f32 accumulate) — final projection only.
// ---------------------------------------------------------------------------
__global__ __launch_bounds__(256) void gemm_bt(const ushort_t* __restrict__ A,
                                               const ushort_t* __restrict__ Bm,
                                               const float* __restrict__ bias,
                                               float* __restrict__ C,
                                               int M, int N, int K) {
  constexpr int KS = 40;
  __shared__ ushort_t As[64][KS];
  __shared__ ushort_t Bs[64][KS];
  const int tid = threadIdx.x;
  const int w = tid >> 6, lane = tid & 63;
  const int wm = w >> 1, wn = w & 1;
  const int m0 = blockIdx.y * 64, n0 = blockIdx.x * 64;

  f32x4 acc[2][2];
#pragma unroll
  for (int i = 0; i < 2; ++i)
#pragma unroll
    for (int j = 0; j < 2; ++j) acc[i][j] = (f32x4){0.f, 0.f, 0.f, 0.f};

  const int sr = tid >> 2, sc = (tid & 3) * 8;
  for (int k0 = 0; k0 < K; k0 += 32) {
    *reinterpret_cast<uint4*>(&As[sr][sc]) =
        *reinterpret_cast<const uint4*>(A + (size_t)(m0 + sr) * K + k0 + sc);
    *reinterpret_cast<uint4*>(&Bs[sr][sc]) =
        *reinterpret_cast<const uint4*>(Bm + (size_t)(n0 + sr) * K + k0 + sc);
    __syncthreads();
    const int fr = lane & 15, koff = (lane >> 4) * 8;
    short8 av[2], bv[2];
#pragma unroll
    for (int f = 0; f < 2; ++f) {
      av[f] = *reinterpret_cast<const short8*>(&As[wm * 32 + f * 16 + fr][koff]);
      bv[f] = *reinterpret_cast<const short8*>(&Bs[wn * 32 + f * 16 + fr][koff]);
    }
#pragma unroll
    for (int fm = 0; fm < 2; ++fm)
#pragma unroll
      for (int fn = 0; fn < 2; ++fn)
        acc[fm][fn] = __builtin_amdgcn_mfma_f32_16x16x32_bf16(av[fm], bv[fn], acc[fm][fn], 0, 0, 0);
    __syncthreads();
  }
  const int cl = lane & 15, rq = (lane >> 4) * 4;
#pragma unroll
  for (int fm = 0; fm < 2; ++fm)
#pragma unroll
    for (int fn = 0; fn < 2; ++fn) {
      int col = n0 + wn * 32 + fn * 16 + cl;
      float bb = bias[col];
#pragma unroll
      for (int j = 0; j < 4; ++j) {
        int row = m0 + wm * 32 + fm * 16 + rq + j;
        C[(size_t)row * N + col] = acc[fm][fn][j] + bb;
      }
    }
}

// ---------------------------------------------------------------------------
// build q/k per-head quantized bf16 + exponent-sign arrays from f32 qkv.
// eq = esig_jax(0.125f * q); ek = esig_jax(k).
// ---------------------------------------------------------------------------
__global__ __launch_bounds__(256) void build_qke(const float* __restrict__ qkv,
                                                 ushort_t* __restrict__ qq,
                                                 ushort_t* __restrict__ qk,
                                                 float* __restrict__ eqr,
                                                 float* __restrict__ ekr) {
  const int HALF = ROWS * CDIM;
  int gid = blockIdx.x * 256 + threadIdx.x;
  int s = (gid >= HALF) ? 1 : 0;
  int rem = gid - s * HALF;
  int row = rem / CDIM, c = rem % CDIM;
  float v = qkv[(size_t)row * 2304 + s * CDIM + c];

  float es = esig_jax(s == 0 ? 0.125f * v : v);
  float xb = bf16rne(v);
  float a = fabsf(xb);
#pragma unroll
  for (int off = 16; off; off >>= 1) a = fmaxf(a, __shfl_xor(a, off, 32));
  int e = flog2(a > 0.f ? a : 1.f);
  float scale = ldexpf(1.f, e - 6);
  ushort_t qb = f2bf(mxq(xb, scale));

  int h = c >> 6, d = c & 63, b = row >> 10, n = row & 1023;
  size_t dst = ((size_t)((b * HEADS + h) << 10) + n) * 64 + d;
  if (s == 0) { qq[dst] = qb; eqr[dst] = es; }
  else        { qk[dst] = qb; ekr[dst] = es; }
}

// ---------------------------------------------------------------------------
// v quantized along N (axis=-2): per (bh, d) column, 32-row blocks.
// ---------------------------------------------------------------------------
__global__ __launch_bounds__(64) void build_qv(const float* __restrict__ qkv,
                                               ushort_t* __restrict__ qv) {
  int bh = blockIdx.x >> 5, nb = blockIdx.x & 31;
  int b = bh / HEADS, h = bh - b * HEADS;
  int d = threadIdx.x;
  float xs[32];
  float am = 0.f;
#pragma unroll
  for (int i = 0; i < 32; ++i) {
    int n = nb * 32 + i;
    float xb = bf16rne(qkv[(size_t)((b << 10) + n) * 2304 + 1536 + h * 64 + d]);
    xs[i] = xb;
    am = fmaxf(am, fabsf(xb));
  }
  int e = flog2(am > 0.f ? am : 1.f);
  float scale = ldexpf(1.f, e - 6);
#pragma unroll
  for (int i = 0; i < 32; ++i)
    qv[((size_t)(bh << 10) + nb * 32 + i) * 64 + d] = f2bf(mxq(xs[i], scale));
}

// ---------------------------------------------------------------------------
// pred[bhc, r, j] = f32 k-seq( eq[r,:] * ek[j,:] )
// ---------------------------------------------------------------------------
__global__ __launch_bounds__(256) void pred_kernel(const float* __restrict__ eqr,
                                                   const float* __restrict__ ekr,
                                                   float* __restrict__ pred,
                                                   int bh0) {
  constexpr int LS = 66;
  __shared__ float eqs[64][LS];
  __shared__ float eks[64][LS];
  int bhc = blockIdx.z, bh = bh0 + bhc;
  int rt = blockIdx.y, kt = blockIdx.x;
  int tid = threadIdx.x;

  const float* eqg = eqr + ((size_t)bh << 16) + (size_t)rt * 64 * 64;
  const float* ekg = ekr + ((size_t)bh << 16) + (size_t)kt * 64 * 64;
#pragma unroll
  for (int it = 0; it < 16; ++it) {
    int flat = it * 256 + tid;
    int r = flat >> 6, d = flat & 63;
    eqs[r][d] = eqg[flat];
    eks[r][d] = ekg[flat];
  }
  __syncthreads();

  int ty = tid >> 4, tx = tid & 15;
  float acc[4][4] = {};
  for (int d = 0; d < 64; d += 2) {
    float da[4][2], db[4][2];
#pragma unroll
    for (int i = 0; i < 4; ++i) {
      float2 t = *reinterpret_cast<const float2*>(&eqs[ty * 4 + i][d]);
      da[i][0] = t.x; da[i][1] = t.y;
      float2 u = *reinterpret_cast<const float2*>(&eks[tx * 4 + i][d]);
      db[i][0] = u.x; db[i][1] = u.y;
    }
#pragma unroll
    for (int i = 0; i < 4; ++i)
#pragma unroll
      for (int j = 0; j < 4; ++j) {
        acc[i][j] = fmaf(da[i][0], db[j][0], acc[i][j]);   // d-ascending
        acc[i][j] = fmaf(da[i][1], db[j][1], acc[i][j]);
      }
  }

  float* po = pred + ((size_t)((bhc << 10) + rt * 64)) * 1024 + kt * 64;
#pragma unroll
  for (int i = 0; i < 4; ++i) {
    float4 o;
    o.x = acc[i][0]; o.y = acc[i][1]; o.z = acc[i][2]; o.w = acc[i][3];
    *reinterpret_cast<float4*>(&po[(size_t)(ty * 4 + i) * 1024 + tx * 4]) = o;
  }
}

// ---------------------------------------------------------------------------
// per row (1 wave): top-20 (value desc, index asc; cached-lane-max scan) ->
// sort asc -> logits: products staged to LDS, per-lane strict k-seq fold ->
// softmax (np-pairwise denom) -> probs bf16 + MX quant -> k-seq P.V ->
// fused output MX quant -> qout (bf16).
// ---------------------------------------------------------------------------
__global__ __launch_bounds__(256) void topk_attn(const float* __restrict__ pred,
                                                 const ushort_t* __restrict__ qq,
                                                 const ushort_t* __restrict__ qk,
                                                 const ushort_t* __restrict__ qv,
                                                 ushort_t* __restrict__ qout,
                                                 int bh0) {
  __shared__ unsigned sidx[4][TOPK];
  __shared__ unsigned sj[4][TOPK];
  __shared__ __align__(16) float plds[4][TOPK][68];

  const int w = threadIdx.x >> 6, lane = threadIdx.x & 63;
  const int rl = blockIdx.x * 4 + w;
  const int bhc = rl >> 10, n = rl & 1023;
  const int bh = bh0 + bhc;
  const int b = bh / HEADS, h = bh - b * HEADS;

  const float* prow = pred + (size_t)rl * 1024;
  unsigned long long key[16];
#pragma unroll
  for (int t = 0; t < 16; ++t) {
    float v = prow[t * 64 + lane];
    key[t] = (((unsigned long long)ordf(v)) << 32) | (unsigned)(1023 - (t * 64 + lane));
  }

  // selection: cached per-lane max; same argmax sequence as full rescan
  unsigned long long lmax = key[0];
#pragma unroll
  for (int t = 1; t < 16; ++t) lmax = (key[t] > lmax) ? key[t] : lmax;
  for (int it = 0; it < TOPK; ++it) {
    unsigned long long m = lmax;
#pragma unroll
    for (int off = 32; off; off >>= 1) {
      unsigned long long o = __shfl_xor(m, off);
      m = (o > m) ? o : m;
    }
    if (lane == 0) sidx[w][it] = 1023u - (unsigned)(m & 0xffffffffu);
    if (lmax == m) {                 // unique owner lane
      unsigned long long nm = 0ull;
#pragma unroll
      for (int t = 0; t < 16; ++t) {
        key[t] = (key[t] == m) ? 0ull : key[t];
        nm = (key[t] > nm) ? key[t] : nm;
      }
      lmax = nm;
    }
  }

  // sort selected indices ascending (indices distinct)
  if (lane < TOPK) {
    unsigned myj0 = sidx[w][lane];
    int rank = 0;
    for (int k2 = 0; k2 < TOPK; ++k2) rank += (sidx[w][k2] < myj0) ? 1 : 0;
    sj[w][rank] = myj0;
  }

  // attn logits: per-lane products staged to LDS; lanes 0..19 fold their
  // key's 64 products in strict k-ascending order.
  float qqv = bf2f(qq[((size_t)(bh << 10) + n) * 64 + lane]);
  for (int i = 0; i < TOPK; ++i) {
    unsigned j = sj[w][i];
    float p = qqv * bf2f(qk[((size_t)(bh << 10) + j) * 64 + lane]);
    plds[w][i][lane] = p;
  }
  __syncthreads();
  float attv = -__builtin_inff();
  if (lane < TOPK) {
    const float4* row4 = reinterpret_cast<const float4*>(&plds[w][lane][0]);
    float s = 0.f;
#pragma unroll
    for (int c = 0; c < 16; ++c) {
      float4 v4 = row4[c];
      s += v4.x; s += v4.y; s += v4.z; s += v4.w;   // k-ascending serial
    }
    attv = s * 0.125f;   // exact pow2 scale
  }

  // softmax max (exact)
  float mx = attv;
#pragma unroll
  for (int off = 32; off; off >>= 1) mx = fmaxf(mx, __shfl_xor(mx, off));
  float ev = (lane < TOPK) ? (float)exp((double)(attv - mx)) : 0.f;

  // np pairwise denominator over the virtual 1024-row: bucket (j>>7, j&7)
  float r = 0.f;
  {
    int Bk = lane >> 3, a = lane & 7;
    for (int i = 0; i < TOPK; ++i) {
      unsigned jj = sj[w][i];
      float evi = __shfl(ev, i);
      if ((int)(jj >> 7) == Bk && (int)(jj & 7) == a) r += evi;
    }
  }
#pragma unroll
  for (int off = 1; off < 64; off <<= 1) r += __shfl_xor(r, off);
  float denom = r;

  float pf = (lane < TOPK) ? (ev / denom) : 0.f;

  // bf16(probs) then MX quant along key axis (j>>5 blocks)
  float pb = bf16rne(pf);
  unsigned myj = (lane < TOPK) ? sj[w][lane] : 0xffffffffu;
  unsigned g = myj >> 5;
  float am = 0.f;
  for (int k2 = 0; k2 < TOPK; ++k2) {
    unsigned oj = __shfl(myj, k2);
    float ov = __shfl(pb, k2);
    if ((oj >> 5) == g) am = fmaxf(am, fabsf(ov));
  }
  int e = flog2(am > 0.f ? am : 1.f);
  float scale = ldexpf(1.f, e - 6);
  float qp = mxq(pb, scale);

  // P.V: k-seq ascending-index fold (lane = d; products exact)
  float o = 0.f;
  for (int i = 0; i < TOPK; ++i) {
    float wq = __shfl(qp, i);
    unsigned j = sj[w][i];
    o = fmaf(wq, bf2f(qv[((size_t)(bh << 10) + j) * 64 + lane]), o);
  }
  float xb2 = bf16rne(o);
  float am2 = fabsf(xb2);
#pragma unroll
  for (int off = 16; off; off >>= 1) am2 = fmaxf(am2, __shfl_xor(am2, off, 32));
  int e2 = flog2(am2 > 0.f ? am2 : 1.f);
  float sc2 = ldexpf(1.f, e2 - 6);
  qout[((size_t)((b << 10) + n)) * CDIM + h * 64 + lane] = f2bf(mxq(xb2, sc2));
}

// ---------------------------------------------------------------------------
// Host launcher
// ---------------------------------------------------------------------------
extern "C" void kernel_launch(void* const* d_in, const int* in_sizes, int n_in,
                              void* d_out, int out_size, void* d_ws, size_t ws_size,
                              hipStream_t stream) {
  (void)in_sizes; (void)n_in; (void)out_size;
  const float* x      = (const float*)d_in[0];
  const float* qkv_w  = (const float*)d_in[1];
  const float* qkv_b  = (const float*)d_in[2];
  const float* proj_w = (const float*)d_in[3];
  const float* proj_b = (const float*)d_in[4];
  float* out = (float*)d_out;

  size_t off = 0;
  auto alloc = [&](size_t bytes) -> void* {
    void* p = (char*)d_ws + off;
    off = (off + bytes + 255) & ~(size_t)255;
    return p;
  };
  ushort_t* qx   = (ushort_t*)alloc((size_t)ROWS * CDIM * 2);
  ushort_t* qw   = (ushort_t*)alloc((size_t)2304 * CDIM * 2);
  ushort_t* qq   = (ushort_t*)alloc((size_t)BHT * SEQ * DH * 2);
  ushort_t* qk   = (ushort_t*)alloc((size_t)BHT * SEQ * DH * 2);
  float*    eqr  = (float*)alloc((size_t)BHT * SEQ * DH * 4);
  float*    ekr  = (float*)alloc((size_t)BHT * SEQ * DH * 4);
  ushort_t* qv   = (ushort_t*)alloc((size_t)BHT * SEQ * DH * 2);
  ushort_t* qout = (ushort_t*)alloc((size_t)ROWS * CDIM * 2);
  ushort_t* qpw  = (ushort_t*)alloc((size_t)CDIM * CDIM * 2);
  float*    qkv  = (float*)alloc((size_t)ROWS * 2304 * 4);

  const size_t per_bh = (size_t)SEQ * SEQ * 4;
  static const int divs[] = {48, 24, 16, 12, 8, 6, 4, 3, 2, 1};
  int CB = 1;
  for (int i = 0; i < 10; ++i)
    if (off + (size_t)divs[i] * per_bh + 256 <= ws_size) { CB = divs[i]; break; }
  float* pred = (float*)alloc((size_t)CB * per_bh);

  // 1) MX quantize inputs
  quant_rows<<<(ROWS * CDIM) / 256, 256, 0, stream>>>(x, qx);
  quant_rows<<<(2304 * CDIM) / 256, 256, 0, stream>>>(qkv_w, qw);
  quant_rows<<<(CDIM * CDIM) / 256, 256, 0, stream>>>(proj_w, qpw);

  // 2) qkv = f32 k-seq(qx @ qw^T) + bias, then per-head builds
  gemm_f32_bt<<<dim3(2304 / 128, ROWS / 128), 256, 0, stream>>>(
      qx, qw, qkv_b, qkv, ROWS, 2304, CDIM);
  build_qke<<<(2 * ROWS * CDIM) / 256, 256, 0, stream>>>(qkv, qq, qk, eqr, ekr);
  build_qv<<<BHT * 32, 64, 0, stream>>>(qkv, qv);

  // 3) chunked: pred + fused topk/attn/softmax/PV/out-quant
  for (int bh0 = 0; bh0 < BHT; bh0 += CB) {
    pred_kernel<<<dim3(16, 16, CB), 256, 0, stream>>>(eqr, ekr, pred, bh0);
    topk_attn<<<CB * (SEQ / 4), 256, 0, stream>>>(pred, qq, qk, qv, qout, bh0);
  }

  // 4) final projection (f32 MFMA — no discrete decisions downstream)
  gemm_bt<<<dim3(CDIM / 64, ROWS / 64), 256, 0, stream>>>(qout, qpw, proj_b, out,
                                                          ROWS, CDIM, CDIM);
}

// Round 21
// 732.470 us; speedup vs baseline: 1.8894x; 1.0026x over previous
//
#include <hip/hip_runtime.h>
#include <hip/hip_bf16.h>
#include <cstdint>
#include <cstddef>

// ---------------------------------------------------------------------------
// QuantizedAttention (MX int8 block quant, exponent-sign top-k mask)
// B=4 N=1024 C=768 H=12 Dh=64 TOPK=20 BLOCK=32
// PASSING semantics (r16+), decision-path numerics preserved BIT-EXACTLY:
//   - exponent_sign = jax-faithful log2: f32(log(f64 x)) / fl32(ln2), floor.
//     eq from 0.125f*q, ek raw. bf16 = RNE. top-k (value desc, index asc).
//     k-seq BLAS sums; np-pairwise softmax denominator; CR exp (f64->f32).
// r21 = performance only: gemm_f32_bt adds register prefetch of the next
// K-tile (loads issued right after the post-write barrier, landing during
// the FMA block -> global latency hidden). Compute chain unchanged ->
// bit-identical qkv.
// ---------------------------------------------------------------------------

typedef __attribute__((ext_vector_type(8))) short short8;
typedef __attribute__((ext_vector_type(8))) unsigned short ushort8;
typedef __attribute__((ext_vector_type(4))) float f32x4;
typedef unsigned short ushort_t;

#define DEV static __device__ __forceinline__

constexpr int BATCH = 4, SEQ = 1024, CDIM = 768, HEADS = 12, DH = 64;
constexpr int ROWS = BATCH * SEQ;          // 4096
constexpr int BHT = BATCH * HEADS;         // 48
constexpr int TOPK = 20;

DEV float bf16rne(float x) {
  unsigned u = __float_as_uint(x);
  u += 0x7fffu + ((u >> 16) & 1u);
  return __uint_as_float(u & 0xffff0000u);
}
DEV ushort_t f2bf(float x) {
  unsigned u = __float_as_uint(x);
  u += 0x7fffu + ((u >> 16) & 1u);
  return (ushort_t)(u >> 16);
}
DEV float bf2f(ushort_t b) { return __uint_as_float(((unsigned)b) << 16); }
// exact floor(log2) — used for MX shared_exp (bf16-valued amax, robust)
DEV int flog2(float ax) { int e; (void)frexpf(ax, &e); return e - 1; }
DEV float mxq(float xb, float scale) {
  float q = rintf(xb / scale);              // round half to even; /pow2 exact
  q = fminf(fmaxf(q, -127.f), 127.f);
  return q * scale;
}
DEV unsigned ordf(float p) {
  if (p == 0.f) return 0x80000000u;
  unsigned u = __float_as_uint(p);
  return (u & 0x80000000u) ? ~u : (u | 0x80000000u);
}

// jax-faithful log2: f32 CR log divided by f32 log(2) constant
DEV float esig_jax(float v) {
  float ax = fabsf(v);
  if (!(ax > 0.f)) return 0.f;
  float lg = (float)log((double)ax);                 // ~CR f32 log
  float l2 = lg / 0.69314718246459960938f;           // f32 division by fl(ln2)
  float fl = floorf(l2);
  return copysignf(exp2f(fl), v);                    // exp2 of integer: exact
}

// ---------------------------------------------------------------------------
// mx_quant(bf16_quant(x), axis=-1) for row-major [R, C], C % 32 == 0.
// ---------------------------------------------------------------------------
__global__ __launch_bounds__(256) void quant_rows(const float* __restrict__ in,
                                                  ushort_t* __restrict__ out) {
  int gid = blockIdx.x * 256 + threadIdx.x;
  float xb = bf16rne(in[gid]);
  float a = fabsf(xb);
#pragma unroll
  for (int off = 16; off; off >>= 1) a = fmaxf(a, __shfl_xor(a, off, 32));
  int e = flog2(a > 0.f ? a : 1.f);
  float scale = ldexpf(1.f, e - 6);
  out[gid] = f2bf(mxq(xb, scale));
}

// ---------------------------------------------------------------------------
// k-sequential f32 GEMM (BLAS model): C = f32seq(A[M,K]*B[N,K]^T) + bias
// 128x128 tile, 256 threads, 8x8 outputs/thread; A-rows = ty + 16*i.
// Register prefetch of next K-tile (issued under the FMA block).
// Per-output: single f32 accumulator, strict k-ascending fmaf —
// bit-identical to r16-r20. Requires M,N % 128 == 0, K % 32 == 0.
// ---------------------------------------------------------------------------
__global__ __launch_bounds__(256) void gemm_f32_bt(const ushort_t* __restrict__ A,
                                                   const ushort_t* __restrict__ Bm,
                                                   const float* __restrict__ bias,
                                                   float* __restrict__ C,
                                                   int M, int N, int K) {
  constexpr int LS = 36;   // f32 stride: 144B rows -> 16B aligned
  __shared__ __align__(16) float As[128][LS];
  __shared__ __align__(16) float Bs[128][LS];
  const int tid = threadIdx.x;
  const int ty = tid >> 4, tx = tid & 15;
  const int m0 = blockIdx.y * 128, n0 = blockIdx.x * 128;
  float acc[8][8] = {};
  const int sr = tid >> 1, sc = (tid & 1) * 16;  // staging: 16 elems/thread

  const ushort_t* ag = A + (size_t)(m0 + sr) * K + sc;
  const ushort_t* bg = Bm + (size_t)(n0 + sr) * K + sc;

  // prologue: load tile 0 into registers
  ushort8 ra0 = *reinterpret_cast<const ushort8*>(ag);
  ushort8 ra1 = *reinterpret_cast<const ushort8*>(ag + 8);
  ushort8 rb0 = *reinterpret_cast<const ushort8*>(bg);
  ushort8 rb1 = *reinterpret_cast<const ushort8*>(bg + 8);

  for (int k0 = 0; k0 < K; k0 += 32) {
    // write current registers (convert bf16 -> f32, exact <<16) to LDS
    {
      float4 f0, f1, f2, f3;
      f0.x = bf2f(ra0.s0); f0.y = bf2f(ra0.s1); f0.z = bf2f(ra0.s2); f0.w = bf2f(ra0.s3);
      f1.x = bf2f(ra0.s4); f1.y = bf2f(ra0.s5); f1.z = bf2f(ra0.s6); f1.w = bf2f(ra0.s7);
      f2.x = bf2f(ra1.s0); f2.y = bf2f(ra1.s1); f2.z = bf2f(ra1.s2); f2.w = bf2f(ra1.s3);
      f3.x = bf2f(ra1.s4); f3.y = bf2f(ra1.s5); f3.z = bf2f(ra1.s6); f3.w = bf2f(ra1.s7);
      *reinterpret_cast<float4*>(&As[sr][sc])      = f0;
      *reinterpret_cast<float4*>(&As[sr][sc + 4])  = f1;
      *reinterpret_cast<float4*>(&As[sr][sc + 8])  = f2;
      *reinterpret_cast<float4*>(&As[sr][sc + 12]) = f3;
      float4 g0, g1, g2, g3;
      g0.x = bf2f(rb0.s0); g0.y = bf2f(rb0.s1); g0.z = bf2f(rb0.s2); g0.w = bf2f(rb0.s3);
      g1.x = bf2f(rb0.s4); g1.y = bf2f(rb0.s5); g1.z = bf2f(rb0.s6); g1.w = bf2f(rb0.s7);
      g2.x = bf2f(rb1.s0); g2.y = bf2f(rb1.s1); g2.z = bf2f(rb1.s2); g2.w = bf2f(rb1.s3);
      g3.x = bf2f(rb1.s4); g3.y = bf2f(rb1.s5); g3.z = bf2f(rb1.s6); g3.w = bf2f(rb1.s7);
      *reinterpret_cast<float4*>(&Bs[sr][sc])      = g0;
      *reinterpret_cast<float4*>(&Bs[sr][sc + 4])  = g1;
      *reinterpret_cast<float4*>(&Bs[sr][sc + 8])  = g2;
      *reinterpret_cast<float4*>(&Bs[sr][sc + 12]) = g3;
    }
    __syncthreads();

    // prefetch next tile (latency hidden under the FMA block below)
    if (k0 + 32 < K) {
      ra0 = *reinterpret_cast<const ushort8*>(ag + k0 + 32);
      ra1 = *reinterpret_cast<const ushort8*>(ag + k0 + 40);
      rb0 = *reinterpret_cast<const ushort8*>(bg + k0 + 32);
      rb1 = *reinterpret_cast<const ushort8*>(bg + k0 + 40);
    }

#pragma unroll
    for (int kk = 0; kk < 32; kk += 4) {
      float4 a4[8];
#pragma unroll
      for (int i = 0; i < 8; ++i)
        a4[i] = *reinterpret_cast<const float4*>(&As[ty + 16 * i][kk]);
#pragma unroll
      for (int j = 0; j < 8; ++j) {
        float4 b4 = *reinterpret_cast<const float4*>(&Bs[j * 16 + tx][kk]);
#pragma unroll
        for (int i = 0; i < 8; ++i) {
          acc[i][j] = fmaf(a4[i].x, b4.x, acc[i][j]);   // k-ascending
          acc[i][j] = fmaf(a4[i].y, b4.y, acc[i][j]);
          acc[i][j] = fmaf(a4[i].z, b4.z, acc[i][j]);
          acc[i][j] = fmaf(a4[i].w, b4.w, acc[i][j]);
        }
      }
    }
    __syncthreads();
  }
#pragma unroll
  for (int i = 0; i < 8; ++i)
#pragma unroll
    for (int j = 0; j < 8; ++j) {
      int row = m0 + ty + 16 * i, col = n0 + j * 16 + tx;
      C[(size_t)row * N + col] = acc[i][j] + bias[col];
    }
}

// ---------------------------------------------------------------------------
// bf16 MFMA GEMM (f32 accumulate) — final projection only.
// ---------------------------------------------------------------------------
__global__ __launch_bounds__(256) void gemm_bt(const ushort_t* __restrict__ A,
                                               const ushort_t* __restrict__ Bm,
                                               const float* __restrict__ bias,
                                               float* __restrict__ C,
                                               int M, int N, int K) {
  constexpr int KS = 40;
  __shared__ ushort_t As[64][KS];
  __shared__ ushort_t Bs[64][KS];
  const int tid = threadIdx.x;
  const int w = tid >> 6, lane = tid & 63;
  const int wm = w >> 1, wn = w & 1;
  const int m0 = blockIdx.y * 64, n0 = blockIdx.x * 64;

  f32x4 acc[2][2];
#pragma unroll
  for (int i = 0; i < 2; ++i)
#pragma unroll
    for (int j = 0; j < 2; ++j) acc[i][j] = (f32x4){0.f, 0.f, 0.f, 0.f};

  const int sr = tid >> 2, sc = (tid & 3) * 8;
  for (int k0 = 0; k0 < K; k0 += 32) {
    *reinterpret_cast<uint4*>(&As[sr][sc]) =
        *reinterpret_cast<const uint4*>(A + (size_t)(m0 + sr) * K + k0 + sc);
    *reinterpret_cast<uint4*>(&Bs[sr][sc]) =
        *reinterpret_cast<const uint4*>(Bm + (size_t)(n0 + sr) * K + k0 + sc);
    __syncthreads();
    const int fr = lane & 15, koff = (lane >> 4) * 8;
    short8 av[2], bv[2];
#pragma unroll
    for (int f = 0; f < 2; ++f) {
      av[f] = *reinterpret_cast<const short8*>(&As[wm * 32 + f * 16 + fr][koff]);
      bv[f] = *reinterpret_cast<const short8*>(&Bs[wn * 32 + f * 16 + fr][koff]);
    }
#pragma unroll
    for (int fm = 0; fm < 2; ++fm)
#pragma unroll
      for (int fn = 0; fn < 2; ++fn)
        acc[fm][fn] = __builtin_amdgcn_mfma_f32_16x16x32_bf16(av[fm], bv[fn], acc[fm][fn], 0, 0, 0);
    __syncthreads();
  }
  const int cl = lane & 15, rq = (lane >> 4) * 4;
#pragma unroll
  for (int fm = 0; fm < 2; ++fm)
#pragma unroll
    for (int fn = 0; fn < 2; ++fn) {
      int col = n0 + wn * 32 + fn * 16 + cl;
      float bb = bias[col];
#pragma unroll
      for (int j = 0; j < 4; ++j) {
        int row = m0 + wm * 32 + fm * 16 + rq + j;
        C[(size_t)row * N + col] = acc[fm][fn][j] + bb;
      }
    }
}

// ---------------------------------------------------------------------------
// build q/k per-head quantized bf16 + exponent-sign arrays from f32 qkv.
// eq = esig_jax(0.125f * q); ek = esig_jax(k).
// ---------------------------------------------------------------------------
__global__ __launch_bounds__(256) void build_qke(const float* __restrict__ qkv,
                                                 ushort_t* __restrict__ qq,
                                                 ushort_t* __restrict__ qk,
                                                 float* __restrict__ eqr,
                                                 float* __restrict__ ekr) {
  const int HALF = ROWS * CDIM;
  int gid = blockIdx.x * 256 + threadIdx.x;
  int s = (gid >= HALF) ? 1 : 0;
  int rem = gid - s * HALF;
  int row = rem / CDIM, c = rem % CDIM;
  float v = qkv[(size_t)row * 2304 + s * CDIM + c];

  float es = esig_jax(s == 0 ? 0.125f * v : v);
  float xb = bf16rne(v);
  float a = fabsf(xb);
#pragma unroll
  for (int off = 16; off; off >>= 1) a = fmaxf(a, __shfl_xor(a, off, 32));
  int e = flog2(a > 0.f ? a : 1.f);
  float scale = ldexpf(1.f, e - 6);
  ushort_t qb = f2bf(mxq(xb, scale));

  int h = c >> 6, d = c & 63, b = row >> 10, n = row & 1023;
  size_t dst = ((size_t)((b * HEADS + h) << 10) + n) * 64 + d;
  if (s == 0) { qq[dst] = qb; eqr[dst] = es; }
  else        { qk[dst] = qb; ekr[dst] = es; }
}

// ---------------------------------------------------------------------------
// v quantized along N (axis=-2): per (bh, d) column, 32-row blocks.
// ---------------------------------------------------------------------------
__global__ __launch_bounds__(64) void build_qv(const float* __restrict__ qkv,
                                               ushort_t* __restrict__ qv) {
  int bh = blockIdx.x >> 5, nb = blockIdx.x & 31;
  int b = bh / HEADS, h = bh - b * HEADS;
  int d = threadIdx.x;
  float xs[32];
  float am = 0.f;
#pragma unroll
  for (int i = 0; i < 32; ++i) {
    int n = nb * 32 + i;
    float xb = bf16rne(qkv[(size_t)((b << 10) + n) * 2304 + 1536 + h * 64 + d]);
    xs[i] = xb;
    am = fmaxf(am, fabsf(xb));
  }
  int e = flog2(am > 0.f ? am : 1.f);
  float scale = ldexpf(1.f, e - 6);
#pragma unroll
  for (int i = 0; i < 32; ++i)
    qv[((size_t)(bh << 10) + nb * 32 + i) * 64 + d] = f2bf(mxq(xs[i], scale));
}

// ---------------------------------------------------------------------------
// pred[bhc, r, j] = f32 k-seq( eq[r,:] * ek[j,:] )
// ---------------------------------------------------------------------------
__global__ __launch_bounds__(256) void pred_kernel(const float* __restrict__ eqr,
                                                   const float* __restrict__ ekr,
                                                   float* __restrict__ pred,
                                                   int bh0) {
  constexpr int LS = 66;
  __shared__ float eqs[64][LS];
  __shared__ float eks[64][LS];
  int bhc = blockIdx.z, bh = bh0 + bhc;
  int rt = blockIdx.y, kt = blockIdx.x;
  int tid = threadIdx.x;

  const float* eqg = eqr + ((size_t)bh << 16) + (size_t)rt * 64 * 64;
  const float* ekg = ekr + ((size_t)bh << 16) + (size_t)kt * 64 * 64;
#pragma unroll
  for (int it = 0; it < 16; ++it) {
    int flat = it * 256 + tid;
    int r = flat >> 6, d = flat & 63;
    eqs[r][d] = eqg[flat];
    eks[r][d] = ekg[flat];
  }
  __syncthreads();

  int ty = tid >> 4, tx = tid & 15;
  float acc[4][4] = {};
  for (int d = 0; d < 64; d += 2) {
    float da[4][2], db[4][2];
#pragma unroll
    for (int i = 0; i < 4; ++i) {
      float2 t = *reinterpret_cast<const float2*>(&eqs[ty * 4 + i][d]);
      da[i][0] = t.x; da[i][1] = t.y;
      float2 u = *reinterpret_cast<const float2*>(&eks[tx * 4 + i][d]);
      db[i][0] = u.x; db[i][1] = u.y;
    }
#pragma unroll
    for (int i = 0; i < 4; ++i)
#pragma unroll
      for (int j = 0; j < 4; ++j) {
        acc[i][j] = fmaf(da[i][0], db[j][0], acc[i][j]);   // d-ascending
        acc[i][j] = fmaf(da[i][1], db[j][1], acc[i][j]);
      }
  }

  float* po = pred + ((size_t)((bhc << 10) + rt * 64)) * 1024 + kt * 64;
#pragma unroll
  for (int i = 0; i < 4; ++i) {
    float4 o;
    o.x = acc[i][0]; o.y = acc[i][1]; o.z = acc[i][2]; o.w = acc[i][3];
    *reinterpret_cast<float4*>(&po[(size_t)(ty * 4 + i) * 1024 + tx * 4]) = o;
  }
}

// ---------------------------------------------------------------------------
// per row (1 wave): top-20 (value desc, index asc; cached-lane-max scan) ->
// sort asc -> logits: products staged to LDS, per-lane strict k-seq fold ->
// softmax (np-pairwise denom) -> probs bf16 + MX quant -> k-seq P.V ->
// fused output MX quant -> qout (bf16).
// ---------------------------------------------------------------------------
__global__ __launch_bounds__(256) void topk_attn(const float* __restrict__ pred,
                                                 const ushort_t* __restrict__ qq,
                                                 const ushort_t* __restrict__ qk,
                                                 const ushort_t* __restrict__ qv,
                                                 ushort_t* __restrict__ qout,
                                                 int bh0) {
  __shared__ unsigned sidx[4][TOPK];
  __shared__ unsigned sj[4][TOPK];
  __shared__ __align__(16) float plds[4][TOPK][68];

  const int w = threadIdx.x >> 6, lane = threadIdx.x & 63;
  const int rl = blockIdx.x * 4 + w;
  const int bhc = rl >> 10, n = rl & 1023;
  const int bh = bh0 + bhc;
  const int b = bh / HEADS, h = bh - b * HEADS;

  const float* prow = pred + (size_t)rl * 1024;
  unsigned long long key[16];
#pragma unroll
  for (int t = 0; t < 16; ++t) {
    float v = prow[t * 64 + lane];
    key[t] = (((unsigned long long)ordf(v)) << 32) | (unsigned)(1023 - (t * 64 + lane));
  }

  // selection: cached per-lane max; same argmax sequence as full rescan
  unsigned long long lmax = key[0];
#pragma unroll
  for (int t = 1; t < 16; ++t) lmax = (key[t] > lmax) ? key[t] : lmax;
  for (int it = 0; it < TOPK; ++it) {
    unsigned long long m = lmax;
#pragma unroll
    for (int off = 32; off; off >>= 1) {
      unsigned long long o = __shfl_xor(m, off);
      m = (o > m) ? o : m;
    }
    if (lane == 0) sidx[w][it] = 1023u - (unsigned)(m & 0xffffffffu);
    if (lmax == m) {                 // unique owner lane
      unsigned long long nm = 0ull;
#pragma unroll
      for (int t = 0; t < 16; ++t) {
        key[t] = (key[t] == m) ? 0ull : key[t];
        nm = (key[t] > nm) ? key[t] : nm;
      }
      lmax = nm;
    }
  }

  // sort selected indices ascending (indices distinct)
  if (lane < TOPK) {
    unsigned myj0 = sidx[w][lane];
    int rank = 0;
    for (int k2 = 0; k2 < TOPK; ++k2) rank += (sidx[w][k2] < myj0) ? 1 : 0;
    sj[w][rank] = myj0;
  }

  // attn logits: per-lane products staged to LDS; lanes 0..19 fold their
  // key's 64 products in strict k-ascending order.
  float qqv = bf2f(qq[((size_t)(bh << 10) + n) * 64 + lane]);
  for (int i = 0; i < TOPK; ++i) {
    unsigned j = sj[w][i];
    float p = qqv * bf2f(qk[((size_t)(bh << 10) + j) * 64 + lane]);
    plds[w][i][lane] = p;
  }
  __syncthreads();
  float attv = -__builtin_inff();
  if (lane < TOPK) {
    const float4* row4 = reinterpret_cast<const float4*>(&plds[w][lane][0]);
    float s = 0.f;
#pragma unroll
    for (int c = 0; c < 16; ++c) {
      float4 v4 = row4[c];
      s += v4.x; s += v4.y; s += v4.z; s += v4.w;   // k-ascending serial
    }
    attv = s * 0.125f;   // exact pow2 scale
  }

  // softmax max (exact)
  float mx = attv;
#pragma unroll
  for (int off = 32; off; off >>= 1) mx = fmaxf(mx, __shfl_xor(mx, off));
  float ev = (lane < TOPK) ? (float)exp((double)(attv - mx)) : 0.f;

  // np pairwise denominator over the virtual 1024-row: bucket (j>>7, j&7)
  float r = 0.f;
  {
    int Bk = lane >> 3, a = lane & 7;
    for (int i = 0; i < TOPK; ++i) {
      unsigned jj = sj[w][i];
      float evi = __shfl(ev, i);
      if ((int)(jj >> 7) == Bk && (int)(jj & 7) == a) r += evi;
    }
  }
#pragma unroll
  for (int off = 1; off < 64; off <<= 1) r += __shfl_xor(r, off);
  float denom = r;

  float pf = (lane < TOPK) ? (ev / denom) : 0.f;

  // bf16(probs) then MX quant along key axis (j>>5 blocks)
  float pb = bf16rne(pf);
  unsigned myj = (lane < TOPK) ? sj[w][lane] : 0xffffffffu;
  unsigned g = myj >> 5;
  float am = 0.f;
  for (int k2 = 0; k2 < TOPK; ++k2) {
    unsigned oj = __shfl(myj, k2);
    float ov = __shfl(pb, k2);
    if ((oj >> 5) == g) am = fmaxf(am, fabsf(ov));
  }
  int e = flog2(am > 0.f ? am : 1.f);
  float scale = ldexpf(1.f, e - 6);
  float qp = mxq(pb, scale);

  // P.V: k-seq ascending-index fold (lane = d; products exact)
  float o = 0.f;
  for (int i = 0; i < TOPK; ++i) {
    float wq = __shfl(qp, i);
    unsigned j = sj[w][i];
    o = fmaf(wq, bf2f(qv[((size_t)(bh << 10) + j) * 64 + lane]), o);
  }
  float xb2 = bf16rne(o);
  float am2 = fabsf(xb2);
#pragma unroll
  for (int off = 16; off; off >>= 1) am2 = fmaxf(am2, __shfl_xor(am2, off, 32));
  int e2 = flog2(am2 > 0.f ? am2 : 1.f);
  float sc2 = ldexpf(1.f, e2 - 6);
  qout[((size_t)((b << 10) + n)) * CDIM + h * 64 + lane] = f2bf(mxq(xb2, sc2));
}

// ---------------------------------------------------------------------------
// Host launcher
// ---------------------------------------------------------------------------
extern "C" void kernel_launch(void* const* d_in, const int* in_sizes, int n_in,
                              void* d_out, int out_size, void* d_ws, size_t ws_size,
                              hipStream_t stream) {
  (void)in_sizes; (void)n_in; (void)out_size;
  const float* x      = (const float*)d_in[0];
  const float* qkv_w  = (const float*)d_in[1];
  const float* qkv_b  = (const float*)d_in[2];
  const float* proj_w = (const float*)d_in[3];
  const float* proj_b = (const float*)d_in[4];
  float* out = (float*)d_out;

  size_t off = 0;
  auto alloc = [&](size_t bytes) -> void* {
    void* p = (char*)d_ws + off;
    off = (off + bytes + 255) & ~(size_t)255;
    return p;
  };
  ushort_t* qx   = (ushort_t*)alloc((size_t)ROWS * CDIM * 2);
  ushort_t* qw   = (ushort_t*)alloc((size_t)2304 * CDIM * 2);
  ushort_t* qq   = (ushort_t*)alloc((size_t)BHT * SEQ * DH * 2);
  ushort_t* qk   = (ushort_t*)alloc((size_t)BHT * SEQ * DH * 2);
  float*    eqr  = (float*)alloc((size_t)BHT * SEQ * DH * 4);
  float*    ekr  = (float*)alloc((size_t)BHT * SEQ * DH * 4);
  ushort_t* qv   = (ushort_t*)alloc((size_t)BHT * SEQ * DH * 2);
  ushort_t* qout = (ushort_t*)alloc((size_t)ROWS * CDIM * 2);
  ushort_t* qpw  = (ushort_t*)alloc((size_t)CDIM * CDIM * 2);
  float*    qkv  = (float*)alloc((size_t)ROWS * 2304 * 4);

  const size_t per_bh = (size_t)SEQ * SEQ * 4;
  static const int divs[] = {48, 24, 16, 12, 8, 6, 4, 3, 2, 1};
  int CB = 1;
  for (int i = 0; i < 10; ++i)
    if (off + (size_t)divs[i] * per_bh + 256 <= ws_size) { CB = divs[i]; break; }
  float* pred = (float*)alloc((size_t)CB * per_bh);

  // 1) MX quantize inputs
  quant_rows<<<(ROWS * CDIM) / 256, 256, 0, stream>>>(x, qx);
  quant_rows<<<(2304 * CDIM) / 256, 256, 0, stream>>>(qkv_w, qw);
  quant_rows<<<(CDIM * CDIM) / 256, 256, 0, stream>>>(proj_w, qpw);

  // 2) qkv = f32 k-seq(qx @ qw^T) + bias, then per-head builds
  gemm_f32_bt<<<dim3(2304 / 128, ROWS / 128), 256, 0, stream>>>(
      qx, qw, qkv_b, qkv, ROWS, 2304, CDIM);
  build_qke<<<(2 * ROWS * CDIM) / 256, 256, 0, stream>>>(qkv, qq, qk, eqr, ekr);
  build_qv<<<BHT * 32, 64, 0, stream>>>(qkv, qv);

  // 3) chunked: pred + fused topk/attn/softmax/PV/out-quant
  for (int bh0 = 0; bh0 < BHT; bh0 += CB) {
    pred_kernel<<<dim3(16, 16, CB), 256, 0, stream>>>(eqr, ekr, pred, bh0);
    topk_attn<<<CB * (SEQ / 4), 256, 0, stream>>>(pred, qq, qk, qv, qout, bh0);
  }

  // 4) final projection (f32 MFMA — no discrete decisions downstream)
  gemm_bt<<<dim3(CDIM / 64, ROWS / 64), 256, 0, stream>>>(qout, qpw, proj_b, out,
                                                          ROWS, CDIM, CDIM);
}